// Round 1
// baseline (1176.968 us; speedup 1.0000x reference)
//
#include <hip/hip_runtime.h>
#include <stdint.h>

typedef unsigned short u16;
typedef unsigned int   u32;
typedef __attribute__((ext_vector_type(8))) short short8;
typedef __attribute__((ext_vector_type(4))) float f32x4;

#define B_   8
#define S_   1024
#define DIN_ 512
#define H_   1024
#define NH_  16
#define HD_  64
#define L_   4
#define M_   (B_*S_)
#define SCALE_ 0.125f
#define EPS_ 1e-5f

__device__ __forceinline__ u16 f2b(float f) {
  u32 u = __builtin_bit_cast(u32, f);
  u32 r = (u + 0x7fffu + ((u >> 16) & 1u)) >> 16;
  return (u16)r;
}
__device__ __forceinline__ float b2f(u16 h) {
  return __builtin_bit_cast(float, (u32)h << 16);
}

__device__ __forceinline__ void gll16(const void* g, void* l) {
  __builtin_amdgcn_global_load_lds(
      (const __attribute__((address_space(1))) u32*)(uintptr_t)g,
      (__attribute__((address_space(3))) u32*)(uintptr_t)l,
      16, 0, 0);
}

// ---------------- fp32 -> bf16 flat convert (4 elems/thread) ----------------
__global__ void cvt_k(const float* __restrict__ in, u16* __restrict__ out) {
  long i = (long)(blockIdx.x * 256 + threadIdx.x) * 4;
  f32x4 v = *(const f32x4*)&in[i];
  u32 p0 = (u32)f2b(v[0]) | ((u32)f2b(v[1]) << 16);
  u32 p1 = (u32)f2b(v[2]) | ((u32)f2b(v[3]) << 16);
  u32* o = (u32*)&out[i];
  o[0] = p0; o[1] = p1;
}

// ---------------- fp32 [R,C] -> bf16 [C,R] transpose-convert ----------------
__global__ __launch_bounds__(256)
void tcvt_k(const float* __restrict__ in, u16* __restrict__ out, int R, int C) {
  __shared__ float t[32][33];
  int tx = threadIdx.x & 31, ty = threadIdx.x >> 5;
  long r0 = blockIdx.y * 32, c0 = blockIdx.x * 32;
#pragma unroll
  for (int i = 0; i < 4; ++i)
    t[ty + i*8][tx] = in[(r0 + ty + i*8) * (long)C + c0 + tx];
  __syncthreads();
#pragma unroll
  for (int i = 0; i < 4; ++i)
    out[(c0 + ty + i*8) * (long)R + r0 + tx] = f2b(t[tx][ty + i*8]);
}

// ---------------- GEMM: C[M,N] = A[M,K] @ Bt[N,K]^T + bias ------------------
// EPI 0: write fp32 Cf and bf16 Cb         (in-proj)
// EPI 1: write bf16 Cb, cols < scale_cols scaled by SCALE_  (QKV)
// EPI 2: write fp32 Cf = acc + bias + Res  (O-proj + residual)
template<int EPI>
__global__ __launch_bounds__(256, 2)
void gemm_k(const u16* __restrict__ A, const u16* __restrict__ Bt,
            const float* __restrict__ bias,
            float* __restrict__ Cf, u16* __restrict__ Cb,
            const float* __restrict__ Res,
            int Ndim, int K, int scale_cols)
{
  __shared__ u16 As[128 * 32];
  __shared__ u16 Bs[128 * 32];
  const int tid = threadIdx.x;
  const int lane = tid & 63;
  const int wid = tid >> 6;
  const int wr = wid >> 1, wc = wid & 1;
  const int l15 = lane & 15, l4 = lane >> 4;
  const long arow0 = (long)blockIdx.x * 128;
  const long brow0 = (long)blockIdx.y * 128;

  f32x4 acc[4][4] = {};

  const int srow = tid >> 2;
  const int scol = (tid & 3) * 8;
  const u16* ga  = A  + (arow0 + srow) * K + scol;
  const u16* ga1 = ga + 64 * (long)K;
  const u16* gb  = Bt + (brow0 + srow) * K + scol;
  const u16* gb1 = gb + 64 * (long)K;
  u16* lA0 = &As[tid * 8];
  u16* lA1 = &As[2048 + tid * 8];
  u16* lB0 = &Bs[tid * 8];
  u16* lB1 = &Bs[2048 + tid * 8];

  for (int k0 = 0; k0 < K; k0 += 32) {
    gll16(ga + k0, lA0);
    gll16(ga1 + k0, lA1);
    gll16(gb + k0, lB0);
    gll16(gb1 + k0, lB1);
    __syncthreads();   // drains vmcnt -> LDS tiles valid
    short8 af[4], bf[4];
#pragma unroll
    for (int m = 0; m < 4; ++m)
      af[m] = *(const short8*)&As[(wr*64 + m*16 + l15) * 32 + l4*8];
#pragma unroll
    for (int n = 0; n < 4; ++n)
      bf[n] = *(const short8*)&Bs[(wc*64 + n*16 + l15) * 32 + l4*8];
#pragma unroll
    for (int m = 0; m < 4; ++m)
#pragma unroll
      for (int n = 0; n < 4; ++n)
        acc[m][n] = __builtin_amdgcn_mfma_f32_16x16x32_bf16(af[m], bf[n], acc[m][n], 0, 0, 0);
    __syncthreads();   // all reads done before next stage overwrites
  }

  const int crow = wr*64 + l4*4;
  const int ccol = wc*64 + l15;
#pragma unroll
  for (int m = 0; m < 4; ++m) {
#pragma unroll
    for (int n = 0; n < 4; ++n) {
      const int col = (int)brow0 + ccol + n*16;
      const float bv = bias[col];
      const float sc = (EPI == 1 && col < scale_cols) ? SCALE_ : 1.0f;
#pragma unroll
      for (int r = 0; r < 4; ++r) {
        const long row = arow0 + crow + m*16 + r;
        float v = acc[m][n][r] + bv;
        if (EPI == 1) {
          Cb[row * Ndim + col] = f2b(v * sc);
        } else if (EPI == 0) {
          Cf[row * Ndim + col] = v;
          Cb[row * Ndim + col] = f2b(v);
        } else {
          Cf[row * Ndim + col] = v + Res[row * Ndim + col];
        }
      }
    }
  }
}

// ---------------- flash attention (bf16 MFMA, online softmax) ----------------
// grid: (S/128, B*NH). 4 waves; wave handles 32 q-rows. KV tiles of 64.
__global__ __launch_bounds__(256, 2)
void attn_k(const u16* __restrict__ qkv, u16* __restrict__ ob)
{
  __shared__ u16 Ks[64 * 64];
  __shared__ u16 Vt[64 * 64];
  __shared__ u16 Ps[4][32 * 64];

  const int tid = threadIdx.x, lane = tid & 63, wid = tid >> 6;
  const int l15 = lane & 15, l4 = lane >> 4;
  const int bh = blockIdx.y;
  const int b = bh >> 4, nh = bh & 15;
  const int q0 = blockIdx.x * 128 + wid * 32;
  const int RS = 3 * H_;
  const long base = (long)b * S_ * RS;
  const u16* Qg = qkv + base + nh * HD_;
  const u16* Kg = qkv + base + H_ + nh * HD_;
  const u16* Vg = qkv + base + 2 * H_ + nh * HD_;

  // Q fragments held in registers for the whole block (already *SCALE_)
  short8 qf[2][2];
#pragma unroll
  for (int i = 0; i < 2; ++i)
#pragma unroll
    for (int kf = 0; kf < 2; ++kf)
      qf[i][kf] = *(const short8*)&Qg[(long)(q0 + i*16 + l15) * RS + kf*32 + l4*8];

  float m_[2] = {-1e30f, -1e30f};
  float l_[2] = {0.f, 0.f};
  f32x4 of[2][4] = {};

  for (int t = 0; t < 16; ++t) {
    const int kv0 = t * 64;
    __syncthreads();
    // stage K tile [64][64] bf16, XOR-swizzled rows
#pragma unroll
    for (int i = 0; i < 2; ++i) {
      int c = tid + i * 256;
      int row = c >> 3, colc = (c & 7) * 8;
      short8 kv = *(const short8*)&Kg[(long)(kv0 + row) * RS + colc];
      int byt = (row*128 + colc*2) ^ ((row & 7) << 4);
      *(short8*)((char*)Ks + byt) = kv;
    }
    // stage V transposed: Vt[d][kv], coalesced global reads per j
#pragma unroll
    for (int i = 0; i < 2; ++i) {
      int c = tid + i * 256;
      int d = c & 63, kvc = (c >> 6) * 8;
      union { u16 u[8]; short8 v; } tv;
#pragma unroll
      for (int j = 0; j < 8; ++j)
        tv.u[j] = Vg[(long)(kv0 + kvc + j) * RS + d];
      int byt = (d*128 + kvc*2) ^ ((d & 7) << 4);
      *(short8*)((char*)Vt + byt) = tv.v;
    }
    __syncthreads();

    // S^T tile: mfma(A=K, B=Q) -> lane: q = l15 (+16i), kv = f*16 + l4*4 + r
    f32x4 sv[2][4];
#pragma unroll
    for (int i = 0; i < 2; ++i)
#pragma unroll
      for (int f = 0; f < 4; ++f)
        sv[i][f] = (f32x4){0.f, 0.f, 0.f, 0.f};
#pragma unroll
    for (int f = 0; f < 4; ++f) {
#pragma unroll
      for (int kf = 0; kf < 2; ++kf) {
        int krow = f*16 + l15;
        int kbyt = (krow*128 + (kf*32 + l4*8)*2) ^ ((krow & 7) << 4);
        short8 kfrag = *(const short8*)((const char*)Ks + kbyt);
#pragma unroll
        for (int i = 0; i < 2; ++i)
          sv[i][f] = __builtin_amdgcn_mfma_f32_16x16x32_bf16(kfrag, qf[i][kf], sv[i][f], 0, 0, 0);
      }
    }

    // online softmax per q-frag
#pragma unroll
    for (int i = 0; i < 2; ++i) {
      float tmax = -1e30f;
#pragma unroll
      for (int f = 0; f < 4; ++f)
#pragma unroll
        for (int r = 0; r < 4; ++r) tmax = fmaxf(tmax, sv[i][f][r]);
      tmax = fmaxf(tmax, __shfl_xor(tmax, 16));
      tmax = fmaxf(tmax, __shfl_xor(tmax, 32));
      const float mnew = fmaxf(m_[i], tmax);
      const float corr = __expf(m_[i] - mnew);
      float tsum = 0.f;
#pragma unroll
      for (int f = 0; f < 4; ++f) {
#pragma unroll
        for (int r = 0; r < 4; ++r) {
          float p = __expf(sv[i][f][r] - mnew);
          sv[i][f][r] = p;
          tsum += p;
        }
      }
      tsum += __shfl_xor(tsum, 16);
      tsum += __shfl_xor(tsum, 32);
      l_[i] = l_[i] * corr + tsum;
      m_[i] = mnew;
      // write P tile (bf16) to per-wave LDS: P[q_local][kv]
#pragma unroll
      for (int f = 0; f < 4; ++f) {
        u32 lo = (u32)f2b(sv[i][f][0]) | ((u32)f2b(sv[i][f][1]) << 16);
        u32 hi = (u32)f2b(sv[i][f][2]) | ((u32)f2b(sv[i][f][3]) << 16);
        int prow = i*16 + l15;
        int pbyt = (prow*128 + (f*16 + l4*4)*2) ^ ((prow & 7) << 4);
        u32* dst = (u32*)((char*)Ps[wid] + pbyt);
        dst[0] = lo; dst[1] = hi;
      }
      // rescale O accumulator rows (rows live at q = l4*4 + r)
#pragma unroll
      for (int r = 0; r < 4; ++r) {
        float cr = __shfl(corr, (lane & 48) | (l4*4 + r));
#pragma unroll
        for (int nf = 0; nf < 4; ++nf) of[i][nf][r] *= cr;
      }
    }
    asm volatile("s_waitcnt lgkmcnt(0)" ::: "memory");

    // O += P @ V  (A=P from per-wave LDS, B=Vt)
#pragma unroll
    for (int kf = 0; kf < 2; ++kf) {
      short8 vf_[4];
#pragma unroll
      for (int nf = 0; nf < 4; ++nf) {
        int vrow = nf*16 + l15;
        int vbyt = (vrow*128 + (kf*32 + l4*8)*2) ^ ((vrow & 7) << 4);
        vf_[nf] = *(const short8*)((const char*)Vt + vbyt);
      }
#pragma unroll
      for (int i = 0; i < 2; ++i) {
        int prow = i*16 + l15;
        int pbyt = (prow*128 + (kf*32 + l4*8)*2) ^ ((prow & 7) << 4);
        short8 pfrag = *(const short8*)((const char*)Ps[wid] + pbyt);
#pragma unroll
        for (int nf = 0; nf < 4; ++nf)
          of[i][nf] = __builtin_amdgcn_mfma_f32_16x16x32_bf16(pfrag, vf_[nf], of[i][nf], 0, 0, 0);
      }
    }
  }

  // normalize and store
#pragma unroll
  for (int i = 0; i < 2; ++i) {
#pragma unroll
    for (int r = 0; r < 4; ++r) {
      float li = __shfl(l_[i], (lane & 48) | (l4*4 + r));
      float inv = 1.0f / li;
      long srow = (long)(b * S_ + q0 + i*16 + l4*4 + r);
#pragma unroll
      for (int nf = 0; nf < 4; ++nf)
        ob[srow * H_ + nh*HD_ + nf*16 + l15] = f2b(of[i][nf][r] * inv);
    }
  }
}

// ---------------- LayerNorm over rows of H=1024 ----------------
__global__ __launch_bounds__(256)
void ln_k(const float* __restrict__ in, const float* __restrict__ g,
          const float* __restrict__ be, float* __restrict__ outf,
          u16* __restrict__ outb)
{
  const int row = blockIdx.x;
  const int tid = threadIdx.x;
  const float* x = in + (long)row * H_;
  f32x4 v = *(const f32x4*)&x[tid * 4];
  float s  = v[0] + v[1] + v[2] + v[3];
  float ss = v[0]*v[0] + v[1]*v[1] + v[2]*v[2] + v[3]*v[3];
#pragma unroll
  for (int o = 1; o < 64; o <<= 1) {
    s  += __shfl_xor(s, o);
    ss += __shfl_xor(ss, o);
  }
  __shared__ float rs[4], rq[4];
  const int wid = tid >> 6;
  if ((tid & 63) == 0) { rs[wid] = s; rq[wid] = ss; }
  __syncthreads();
  float ts = rs[0] + rs[1] + rs[2] + rs[3];
  float tq = rq[0] + rq[1] + rq[2] + rq[3];
  const float mu = ts * (1.0f / H_);
  const float var = tq * (1.0f / H_) - mu * mu;
  const float rstd = rsqrtf(var + EPS_);
  const long obase = (long)row * H_ + tid * 4;
#pragma unroll
  for (int j = 0; j < 4; ++j) {
    int c = tid * 4 + j;
    float y = (v[j] - mu) * rstd * g[c] + be[c];
    outf[obase + j] = y;
    if (outb) outb[obase + j] = f2b(y);
  }
}

// ---------------- mean-pool over S ----------------
__global__ void pool_k(const float* __restrict__ hf, float* __restrict__ pooled) {
  const int c = blockIdx.x * 256 + threadIdx.x;
  const int b = blockIdx.y;
  float s = 0.f;
  for (int t = 0; t < S_; ++t) s += hf[((long)(b * S_ + t)) * H_ + c];
  pooled[b * H_ + c] = s * (1.0f / S_);
}

// ---------------- small final GEMM (fp32): tmp[b,n] = pooled[b,:]@W[:,n]+bias ----
__global__ void fgemm_k(const float* __restrict__ pooled, const float* __restrict__ W,
                        const float* __restrict__ bias, float* __restrict__ out) {
  const int n = blockIdx.x * 256 + threadIdx.x;
  const int b = blockIdx.y;
  float s = bias[n];
  for (int k = 0; k < H_; ++k) s += pooled[b * H_ + k] * W[(long)k * H_ + n];
  out[b * H_ + n] = s;
}

extern "C" void kernel_launch(void* const* d_in, const int* in_sizes, int n_in,
                              void* d_out, int out_size, void* d_ws, size_t ws_size,
                              hipStream_t stream) {
  const float* x     = (const float*)d_in[0];
  const float* W_in  = (const float*)d_in[1];
  const float* b_in  = (const float*)d_in[2];
  const float* W_qkv = (const float*)d_in[3];
  const float* b_qkv = (const float*)d_in[4];
  const float* W_o   = (const float*)d_in[5];
  const float* b_o   = (const float*)d_in[6];
  const float* g1    = (const float*)d_in[7];
  const float* be1   = (const float*)d_in[8];
  const float* W_out = (const float*)d_in[9];
  const float* b_out = (const float*)d_in[10];
  const float* g2    = (const float*)d_in[11];
  const float* be2   = (const float*)d_in[12];
  float* outp = (float*)d_out;

  char* ws = (char*)d_ws;
  float* hf    = (float*)(ws + 0);            // 33.55 MB
  u16*   hb    = (u16*)(ws + 33554432);       // 16.78 MB
  u16*   qkvb  = (u16*)(ws + 50331648);       // 50.33 MB
  float* resf  = (float*)(ws + 50331648);     // aliases qkvb (disjoint in time)
  u16*   ob    = (u16*)(ws + 100663296);      // 16.78 MB
  u16*   xb    = (u16*)(ws + 100663296);      // aliases ob (xb dead before attn)
  u16*   WinT  = (u16*)(ws + 117440512);      // 1.05 MB
  u16*   WqkvT = (u16*)(ws + 118489088);      // 25.17 MB
  u16*   WoT   = (u16*)(ws + 143654912);      // 8.39 MB
  float* pooled= (float*)(ws + 152043520);
  float* tmpf  = (float*)(ws + 152076288);

  // convert input + weights to bf16 (weights transposed to [N,K])
  cvt_k<<<dim3(M_ * DIN_ / 1024), 256, 0, stream>>>(x, xb);
  tcvt_k<<<dim3(H_/32, DIN_/32), 256, 0, stream>>>(W_in, WinT, DIN_, H_);
  for (int l = 0; l < L_; ++l) {
    tcvt_k<<<dim3(3*H_/32, H_/32), 256, 0, stream>>>(W_qkv + (size_t)l*H_*3*H_,
                                                     WqkvT + (size_t)l*3*H_*H_, H_, 3*H_);
    tcvt_k<<<dim3(H_/32, H_/32), 256, 0, stream>>>(W_o + (size_t)l*H_*H_,
                                                   WoT + (size_t)l*H_*H_, H_, H_);
  }

  // h = x @ W_in + b_in   (fp32 + bf16 copies)
  gemm_k<0><<<dim3(M_/128, H_/128), 256, 0, stream>>>(xb, WinT, b_in, hf, hb, nullptr, H_, DIN_, 0);

  for (int l = 0; l < L_; ++l) {
    gemm_k<1><<<dim3(M_/128, 3*H_/128), 256, 0, stream>>>(hb, WqkvT + (size_t)l*3*H_*H_,
                                                          b_qkv + l*3*H_, nullptr, qkvb, nullptr,
                                                          3*H_, H_, H_);
    attn_k<<<dim3(S_/128, B_*NH_), 256, 0, stream>>>(qkvb, ob);
    gemm_k<2><<<dim3(M_/128, H_/128), 256, 0, stream>>>(ob, WoT + (size_t)l*H_*H_,
                                                        b_o + l*H_, resf, nullptr, hf,
                                                        H_, H_, 0);
    ln_k<<<dim3(M_), 256, 0, stream>>>(resf, g1 + l*H_, be1 + l*H_, hf, hb);
  }

  pool_k<<<dim3(H_/256, B_), 256, 0, stream>>>(hf, pooled);
  fgemm_k<<<dim3(H_/256, B_), 256, 0, stream>>>(pooled, W_out, b_out, tmpf);
  ln_k<<<dim3(B_), 256, 0, stream>>>(tmpf, g2, be2, outp, nullptr);
}

// Round 2
// 1085.088 us; speedup vs baseline: 1.0847x; 1.0847x over previous
//
#include <hip/hip_runtime.h>
#include <stdint.h>

typedef unsigned short u16;
typedef unsigned int   u32;
typedef __attribute__((ext_vector_type(8))) short short8;
typedef __attribute__((ext_vector_type(4))) float f32x4;

#define B_   8
#define S_   1024
#define DIN_ 512
#define H_   1024
#define NH_  16
#define HD_  64
#define L_   4
#define M_   (B_*S_)
#define SCALE_ 0.125f
#define EPS_ 1e-5f

__device__ __forceinline__ u16 f2b(float f) {
  u32 u = __builtin_bit_cast(u32, f);
  u32 r = (u + 0x7fffu + ((u >> 16) & 1u)) >> 16;
  return (u16)r;
}

__device__ __forceinline__ void gll16(const void* g, void* l) {
  __builtin_amdgcn_global_load_lds(
      (const __attribute__((address_space(1))) u32*)(uintptr_t)g,
      (__attribute__((address_space(3))) u32*)(uintptr_t)l,
      16, 0, 0);
}

// ---------------- fp32 -> bf16 flat convert (4 elems/thread) ----------------
__global__ void cvt_k(const float* __restrict__ in, u16* __restrict__ out) {
  long i = (long)(blockIdx.x * 256 + threadIdx.x) * 4;
  f32x4 v = *(const f32x4*)&in[i];
  u32 p0 = (u32)f2b(v[0]) | ((u32)f2b(v[1]) << 16);
  u32 p1 = (u32)f2b(v[2]) | ((u32)f2b(v[3]) << 16);
  u32* o = (u32*)&out[i];
  o[0] = p0; o[1] = p1;
}

// -------- fp32 [R,C] -> bf16 [C,R] transpose-convert, batched over z --------
__global__ __launch_bounds__(256)
void tcvt_k(const float* __restrict__ in0, u16* __restrict__ out0, int R, int C) {
  __shared__ float t[32][33];
  const float* in = in0 + (size_t)blockIdx.z * R * C;
  u16* out = out0 + (size_t)blockIdx.z * R * C;
  int tx = threadIdx.x & 31, ty = threadIdx.x >> 5;
  long r0 = blockIdx.y * 32, c0 = blockIdx.x * 32;
#pragma unroll
  for (int i = 0; i < 4; ++i)
    t[ty + i*8][tx] = in[(r0 + ty + i*8) * (long)C + c0 + tx];
  __syncthreads();
#pragma unroll
  for (int i = 0; i < 4; ++i)
    out[(c0 + ty + i*8) * (long)R + r0 + tx] = f2b(t[tx][ty + i*8]);
}

// ---------------- GEMM: C[M,N] = A[M,K] @ Bt[N,K]^T + bias ------------------
template<int EPI>
__global__ __launch_bounds__(256, 2)
void gemm_k(const u16* __restrict__ A, const u16* __restrict__ Bt,
            const float* __restrict__ bias,
            float* __restrict__ Cf, u16* __restrict__ Cb,
            const float* __restrict__ Res,
            int Ndim, int K, int scale_cols)
{
  __shared__ u16 As[128 * 32];
  __shared__ u16 Bs[128 * 32];
  const int tid = threadIdx.x;
  const int lane = tid & 63;
  const int wid = tid >> 6;
  const int wr = wid >> 1, wc = wid & 1;
  const int l15 = lane & 15, l4 = lane >> 4;
  const long arow0 = (long)blockIdx.x * 128;
  const long brow0 = (long)blockIdx.y * 128;

  f32x4 acc[4][4] = {};

  const int srow = tid >> 2;
  const int scol = (tid & 3) * 8;
  const u16* ga  = A  + (arow0 + srow) * K + scol;
  const u16* ga1 = ga + 64 * (long)K;
  const u16* gb  = Bt + (brow0 + srow) * K + scol;
  const u16* gb1 = gb + 64 * (long)K;
  u16* lA0 = &As[tid * 8];
  u16* lA1 = &As[2048 + tid * 8];
  u16* lB0 = &Bs[tid * 8];
  u16* lB1 = &Bs[2048 + tid * 8];

  for (int k0 = 0; k0 < K; k0 += 32) {
    gll16(ga + k0, lA0);
    gll16(ga1 + k0, lA1);
    gll16(gb + k0, lB0);
    gll16(gb1 + k0, lB1);
    __syncthreads();
    short8 af[4], bf[4];
#pragma unroll
    for (int m = 0; m < 4; ++m)
      af[m] = *(const short8*)&As[(wr*64 + m*16 + l15) * 32 + l4*8];
#pragma unroll
    for (int n = 0; n < 4; ++n)
      bf[n] = *(const short8*)&Bs[(wc*64 + n*16 + l15) * 32 + l4*8];
#pragma unroll
    for (int m = 0; m < 4; ++m)
#pragma unroll
      for (int n = 0; n < 4; ++n)
        acc[m][n] = __builtin_amdgcn_mfma_f32_16x16x32_bf16(af[m], bf[n], acc[m][n], 0, 0, 0);
    __syncthreads();
  }

  const int crow = wr*64 + l4*4;
  const int ccol = wc*64 + l15;
#pragma unroll
  for (int m = 0; m < 4; ++m) {
#pragma unroll
    for (int n = 0; n < 4; ++n) {
      const int col = (int)brow0 + ccol + n*16;
      const float bv = bias[col];
      const float sc = (EPI == 1 && col < scale_cols) ? SCALE_ : 1.0f;
#pragma unroll
      for (int r = 0; r < 4; ++r) {
        const long row = arow0 + crow + m*16 + r;
        float v = acc[m][n][r] + bv;
        if (EPI == 1) {
          Cb[row * Ndim + col] = f2b(v * sc);
        } else if (EPI == 0) {
          Cf[row * Ndim + col] = v;
          Cb[row * Ndim + col] = f2b(v);
        } else {
          Cf[row * Ndim + col] = v + Res[row * Ndim + col];
        }
      }
    }
  }
}

// ---------------- flash attention v2: double-buffered, XCD-grouped ----------
// grid: 1024 blocks x 256 threads. Wave owns 32 q-rows. KV tiles of 64.
// LDS 48KB -> 3 blocks/CU. K staged via global_load_lds w/ pre-swizzled src;
// V staged via regs (issued before compute) -> swizzled ds_write after.
__global__ __launch_bounds__(256, 3)
void attn_k(const u16* __restrict__ qkv, u16* __restrict__ ob)
{
  __shared__ u16 Ks[2][4096];   // [64 kv][64 d], XOR-swizzled content
  __shared__ u16 Vs[2][4096];   // [64 d][64 kv] (transposed), XOR-swizzled
  __shared__ u16 Ps[4][2048];   // per-wave P tile [32 q][64 kv], swizzled

  const int tid = threadIdx.x, lane = tid & 63, wid = tid >> 6;
  const int l15 = lane & 15, l4 = lane >> 4;

  // XCD grouping: all 8 q-blocks of a head land on one XCD (head%8).
  const int hb = blockIdx.x;
  const int xcd = hb & 7, slot = hb >> 3;
  const int bh = xcd + ((slot >> 3) << 3);   // head index 0..127
  const int qx = slot & 7;                   // q-tile index 0..7
  const int b = bh >> 4, nh = bh & 15;
  const int q0 = qx * 128 + wid * 32;

  const int RS = 3 * H_;
  const long base = (long)b * S_ * RS;
  const u16* Qg = qkv + base + nh * HD_;
  const u16* Kg = qkv + base + H_ + nh * HD_;
  const u16* Vg = qkv + base + 2 * H_ + nh * HD_;

  // Q fragments in registers for the whole block (QKV GEMM pre-scaled q)
  short8 qf[2][2];
#pragma unroll
  for (int i = 0; i < 2; ++i)
#pragma unroll
    for (int kf = 0; kf < 2; ++kf)
      qf[i][kf] = *(const short8*)&Qg[(long)(q0 + i*16 + l15) * RS + kf*32 + l4*8];

  float m_[2] = {-1e30f, -1e30f};
  float l_[2] = {0.f, 0.f};
  f32x4 of[2][4] = {};

  const int vd = tid & 63;          // V staging: this thread's d column
  const int vk0 = (tid >> 6) * 8;   // kv chunk base (iter 0); +32 for iter 1
  const int vbyt0 = (vd*128 + (tid>>6)*16) ^ ((vd & 7) << 4);
  const int vbyt1 = (vd*128 + ((tid>>6)+4)*16) ^ ((vd & 7) << 4);

  // ---- prologue: stage tile 0 into buffer 0 ----
  {
#pragma unroll
    for (int i = 0; i < 2; ++i) {
      int c = (i*4 + wid) * 64 + lane;
      int row = c >> 3;
      int sc2 = (lane & 7) ^ (row & 7);
      gll16(Kg + (long)row * RS + sc2*8, (char*)&Ks[0][0] + (size_t)c*16);
    }
    union { u16 u[8]; short8 v; } ta, tb;
#pragma unroll
    for (int j = 0; j < 8; ++j) {
      ta.u[j] = Vg[(long)(vk0 + j) * RS + vd];
      tb.u[j] = Vg[(long)(vk0 + 32 + j) * RS + vd];
    }
    *(short8*)((char*)&Vs[0][0] + vbyt0) = ta.v;
    *(short8*)((char*)&Vs[0][0] + vbyt1) = tb.v;
  }
  __syncthreads();

  for (int t = 0; t < 16; ++t) {
    const int cur = t & 1, nxt = cur ^ 1;
    union { u16 u[8]; short8 v; } ta, tb;
    if (t < 15) {
      const int kv1 = (t + 1) * 64;
      // issue K staging for next tile (direct to LDS, pre-swizzled source)
#pragma unroll
      for (int i = 0; i < 2; ++i) {
        int c = (i*4 + wid) * 64 + lane;
        int row = c >> 3;
        int sc2 = (lane & 7) ^ (row & 7);
        gll16(Kg + (long)(kv1 + row) * RS + sc2*8, (char*)&Ks[nxt][0] + (size_t)c*16);
      }
      // issue V loads for next tile into registers (drained after compute)
#pragma unroll
      for (int j = 0; j < 8; ++j) {
        ta.u[j] = Vg[(long)(kv1 + vk0 + j) * RS + vd];
        tb.u[j] = Vg[(long)(kv1 + vk0 + 32 + j) * RS + vd];
      }
    }

    // ==== QK^T from Ks[cur]: sv = S^T fragments, lane: q=l15, kv=f*16+l4*4+r
    f32x4 sv[2][4];
#pragma unroll
    for (int i = 0; i < 2; ++i)
#pragma unroll
      for (int f = 0; f < 4; ++f)
        sv[i][f] = (f32x4){0.f, 0.f, 0.f, 0.f};
    __builtin_amdgcn_s_setprio(1);
#pragma unroll
    for (int f = 0; f < 4; ++f) {
#pragma unroll
      for (int kf = 0; kf < 2; ++kf) {
        int krow = f*16 + l15;
        int kbyt = (krow*128 + (kf*32 + l4*8)*2) ^ ((krow & 7) << 4);
        short8 kfrag = *(const short8*)((const char*)&Ks[cur][0] + kbyt);
#pragma unroll
        for (int i = 0; i < 2; ++i)
          sv[i][f] = __builtin_amdgcn_mfma_f32_16x16x32_bf16(kfrag, qf[i][kf], sv[i][f], 0, 0, 0);
      }
    }
    __builtin_amdgcn_s_setprio(0);

    // ==== online softmax ====
#pragma unroll
    for (int i = 0; i < 2; ++i) {
      float tmax = -1e30f;
#pragma unroll
      for (int f = 0; f < 4; ++f)
#pragma unroll
        for (int r = 0; r < 4; ++r) tmax = fmaxf(tmax, sv[i][f][r]);
      tmax = fmaxf(tmax, __shfl_xor(tmax, 16));
      tmax = fmaxf(tmax, __shfl_xor(tmax, 32));
      const float mnew = fmaxf(m_[i], tmax);
      const float corr = __expf(m_[i] - mnew);
      float tsum = 0.f;
#pragma unroll
      for (int f = 0; f < 4; ++f) {
#pragma unroll
        for (int r = 0; r < 4; ++r) {
          float p = __expf(sv[i][f][r] - mnew);
          sv[i][f][r] = p;
          tsum += p;
        }
      }
      tsum += __shfl_xor(tsum, 16);
      tsum += __shfl_xor(tsum, 32);
      l_[i] = l_[i] * corr + tsum;
      m_[i] = mnew;
#pragma unroll
      for (int f = 0; f < 4; ++f) {
        u32 lo = (u32)f2b(sv[i][f][0]) | ((u32)f2b(sv[i][f][1]) << 16);
        u32 hi = (u32)f2b(sv[i][f][2]) | ((u32)f2b(sv[i][f][3]) << 16);
        int prow = i*16 + l15;
        int pbyt = (prow*128 + (f*16 + l4*4)*2) ^ ((prow & 7) << 4);
        u32* dst = (u32*)((char*)&Ps[wid][0] + pbyt);
        dst[0] = lo; dst[1] = hi;
      }
#pragma unroll
      for (int r = 0; r < 4; ++r) {
        float cr = __shfl(corr, (lane & 48) | (l4*4 + r));
#pragma unroll
        for (int nf = 0; nf < 4; ++nf) of[i][nf][r] *= cr;
      }
    }
    asm volatile("s_waitcnt lgkmcnt(0)" ::: "memory");
    __builtin_amdgcn_sched_barrier(0);

    // ==== O += P @ V from Ps[wid], Vs[cur] ====
    __builtin_amdgcn_s_setprio(1);
#pragma unroll
    for (int kf = 0; kf < 2; ++kf) {
      short8 vf_[4];
#pragma unroll
      for (int nf = 0; nf < 4; ++nf) {
        int vrow = nf*16 + l15;
        int vbyt = (vrow*128 + (kf*32 + l4*8)*2) ^ ((vrow & 7) << 4);
        vf_[nf] = *(const short8*)((const char*)&Vs[cur][0] + vbyt);
      }
#pragma unroll
      for (int i = 0; i < 2; ++i) {
        int prow = i*16 + l15;
        int pbyt = (prow*128 + (kf*32 + l4*8)*2) ^ ((prow & 7) << 4);
        short8 pfrag = *(const short8*)((const char*)&Ps[wid][0] + pbyt);
#pragma unroll
        for (int nf = 0; nf < 4; ++nf)
          of[i][nf] = __builtin_amdgcn_mfma_f32_16x16x32_bf16(pfrag, vf_[nf], of[i][nf], 0, 0, 0);
      }
    }
    __builtin_amdgcn_s_setprio(0);

    if (t < 15) {
      // drain V loads (compiler waits on reg deps) and publish to Vs[nxt]
      *(short8*)((char*)&Vs[nxt][0] + vbyt0) = ta.v;
      *(short8*)((char*)&Vs[nxt][0] + vbyt1) = tb.v;
      __syncthreads();   // also drains gll16 vmcnt -> Ks[nxt] valid
    }
  }

  // normalize and store
#pragma unroll
  for (int i = 0; i < 2; ++i) {
#pragma unroll
    for (int r = 0; r < 4; ++r) {
      float li = __shfl(l_[i], (lane & 48) | (l4*4 + r));
      float inv = 1.0f / li;
      long srow = (long)(b * S_ + q0 + i*16 + l4*4 + r);
#pragma unroll
      for (int nf = 0; nf < 4; ++nf)
        ob[srow * H_ + nh*HD_ + nf*16 + l15] = f2b(of[i][nf][r] * inv);
    }
  }
}

// ---------------- LayerNorm over rows of H=1024 ----------------
__global__ __launch_bounds__(256)
void ln_k(const float* __restrict__ in, const float* __restrict__ g,
          const float* __restrict__ be, float* __restrict__ outf,
          u16* __restrict__ outb)
{
  const int row = blockIdx.x;
  const int tid = threadIdx.x;
  const float* x = in + (long)row * H_;
  f32x4 v = *(const f32x4*)&x[tid * 4];
  float s  = v[0] + v[1] + v[2] + v[3];
  float ss = v[0]*v[0] + v[1]*v[1] + v[2]*v[2] + v[3]*v[3];
#pragma unroll
  for (int o = 1; o < 64; o <<= 1) {
    s  += __shfl_xor(s, o);
    ss += __shfl_xor(ss, o);
  }
  __shared__ float rs[4], rq[4];
  const int wid = tid >> 6;
  if ((tid & 63) == 0) { rs[wid] = s; rq[wid] = ss; }
  __syncthreads();
  float ts = rs[0] + rs[1] + rs[2] + rs[3];
  float tq = rq[0] + rq[1] + rq[2] + rq[3];
  const float mu = ts * (1.0f / H_);
  const float var = tq * (1.0f / H_) - mu * mu;
  const float rstd = rsqrtf(var + EPS_);
  const long obase = (long)row * H_ + tid * 4;
#pragma unroll
  for (int j = 0; j < 4; ++j) {
    int c = tid * 4 + j;
    float y = (v[j] - mu) * rstd * g[c] + be[c];
    outf[obase + j] = y;
    if (outb) outb[obase + j] = f2b(y);
  }
}

// ---------------- mean-pool over S (partials + atomic) ----------------
__global__ void pool_k(const float* __restrict__ hf, float* __restrict__ pooled) {
  const int c = blockIdx.x * 256 + threadIdx.x;
  const int b = blockIdx.y;
  const int s0 = blockIdx.z * 128;
  float s = 0.f;
  for (int t = 0; t < 128; ++t) s += hf[((long)(b * S_ + s0 + t)) * H_ + c];
  atomicAdd(&pooled[b * H_ + c], s * (1.0f / S_));
}

// ---------------- small final GEMM (fp32) ----------------
__global__ void fgemm_k(const float* __restrict__ pooled, const float* __restrict__ W,
                        const float* __restrict__ bias, float* __restrict__ out) {
  const int n = blockIdx.x * 256 + threadIdx.x;
  const int b = blockIdx.y;
  float s = bias[n];
  for (int k = 0; k < H_; ++k) s += pooled[b * H_ + k] * W[(long)k * H_ + n];
  out[b * H_ + n] = s;
}

extern "C" void kernel_launch(void* const* d_in, const int* in_sizes, int n_in,
                              void* d_out, int out_size, void* d_ws, size_t ws_size,
                              hipStream_t stream) {
  const float* x     = (const float*)d_in[0];
  const float* W_in  = (const float*)d_in[1];
  const float* b_in  = (const float*)d_in[2];
  const float* W_qkv = (const float*)d_in[3];
  const float* b_qkv = (const float*)d_in[4];
  const float* W_o   = (const float*)d_in[5];
  const float* b_o   = (const float*)d_in[6];
  const float* g1    = (const float*)d_in[7];
  const float* be1   = (const float*)d_in[8];
  const float* W_out = (const float*)d_in[9];
  const float* b_out = (const float*)d_in[10];
  const float* g2    = (const float*)d_in[11];
  const float* be2   = (const float*)d_in[12];
  float* outp = (float*)d_out;

  char* ws = (char*)d_ws;
  float* hf    = (float*)(ws + 0);            // 33.55 MB
  u16*   hb    = (u16*)(ws + 33554432);       // 16.78 MB
  u16*   qkvb  = (u16*)(ws + 50331648);       // 50.33 MB
  float* resf  = (float*)(ws + 50331648);     // aliases qkvb (disjoint in time)
  u16*   ob    = (u16*)(ws + 100663296);      // 16.78 MB
  u16*   xb    = (u16*)(ws + 100663296);      // aliases ob (xb dead before attn)
  u16*   WinT  = (u16*)(ws + 117440512);      // 1.05 MB
  u16*   WqkvT = (u16*)(ws + 118489088);      // 25.17 MB
  u16*   WoT   = (u16*)(ws + 143654912);      // 8.39 MB
  float* pooled= (float*)(ws + 152043520);
  float* tmpf  = (float*)(ws + 152076288);

  // convert input + weights to bf16 (weights transposed to [N,K]), batched
  cvt_k<<<dim3(M_ * DIN_ / 1024), 256, 0, stream>>>(x, xb);
  tcvt_k<<<dim3(H_/32, DIN_/32, 1), 256, 0, stream>>>(W_in, WinT, DIN_, H_);
  tcvt_k<<<dim3(3*H_/32, H_/32, L_), 256, 0, stream>>>(W_qkv, WqkvT, H_, 3*H_);
  tcvt_k<<<dim3(H_/32, H_/32, L_), 256, 0, stream>>>(W_o, WoT, H_, H_);

  // h = x @ W_in + b_in   (fp32 + bf16 copies)
  gemm_k<0><<<dim3(M_/128, H_/128), 256, 0, stream>>>(xb, WinT, b_in, hf, hb, nullptr, H_, DIN_, 0);

  for (int l = 0; l < L_; ++l) {
    gemm_k<1><<<dim3(M_/128, 3*H_/128), 256, 0, stream>>>(hb, WqkvT + (size_t)l*3*H_*H_,
                                                          b_qkv + l*3*H_, nullptr, qkvb, nullptr,
                                                          3*H_, H_, H_);
    attn_k<<<dim3(S_/128 * B_ * NH_), 256, 0, stream>>>(qkvb, ob);
    gemm_k<2><<<dim3(M_/128, H_/128), 256, 0, stream>>>(ob, WoT + (size_t)l*H_*H_,
                                                        b_o + l*H_, resf, nullptr, hf,
                                                        H_, H_, 0);
    ln_k<<<dim3(M_), 256, 0, stream>>>(resf, g1 + l*H_, be1 + l*H_, hf, hb);
  }

  hipMemsetAsync(pooled, 0, B_ * H_ * sizeof(float), stream);
  pool_k<<<dim3(H_/256, B_, 8), 256, 0, stream>>>(hf, pooled);
  fgemm_k<<<dim3(H_/256, B_), 256, 0, stream>>>(pooled, W_out, b_out, tmpf);
  ln_k<<<dim3(B_), 256, 0, stream>>>(tmpf, g2, be2, outp, nullptr);
}

// Round 5
// 951.648 us; speedup vs baseline: 1.2368x; 1.1402x over previous
//
#include <hip/hip_runtime.h>
#include <stdint.h>

typedef unsigned short u16;
typedef unsigned int   u32;
typedef __attribute__((ext_vector_type(8))) short short8;
typedef __attribute__((ext_vector_type(4))) float f32x4;
typedef __attribute__((ext_vector_type(16))) float f32x16;
typedef __attribute__((ext_vector_type(2))) unsigned int uint2v;

#define B_   8
#define S_   1024
#define DIN_ 512
#define H_   1024
#define NH_  16
#define HD_  64
#define L_   4
#define M_   (B_*S_)
#define SCALE_ 0.125f
#define EPS_ 1e-5f

__device__ __forceinline__ u16 f2b(float f) {
  u32 u = __builtin_bit_cast(u32, f);
  u32 r = (u + 0x7fffu + ((u >> 16) & 1u)) >> 16;
  return (u16)r;
}

__device__ __forceinline__ u32 cvtpk(float lo, float hi) {
  u32 r;
  asm("v_cvt_pk_bf16_f32 %0, %1, %2" : "=v"(r) : "v"(lo), "v"(hi));
  return r;
}

__device__ __forceinline__ void gll16(const void* g, void* l) {
  __builtin_amdgcn_global_load_lds(
      (const __attribute__((address_space(1))) u32*)(uintptr_t)g,
      (__attribute__((address_space(3))) u32*)(uintptr_t)l,
      16, 0, 0);
}

// ---------------- fp32 -> bf16 flat convert (4 elems/thread) ----------------
__global__ void cvt_k(const float* __restrict__ in, u16* __restrict__ out) {
  long i = (long)(blockIdx.x * 256 + threadIdx.x) * 4;
  f32x4 v = *(const f32x4*)&in[i];
  u32 p0 = (u32)f2b(v[0]) | ((u32)f2b(v[1]) << 16);
  u32 p1 = (u32)f2b(v[2]) | ((u32)f2b(v[3]) << 16);
  u32* o = (u32*)&out[i];
  o[0] = p0; o[1] = p1;
}

// -------- fp32 [R,C] -> bf16 [C,R] transpose-convert, batched over z --------
__global__ __launch_bounds__(256)
void tcvt_k(const float* __restrict__ in0, u16* __restrict__ out0, int R, int C) {
  __shared__ float t[32][33];
  const float* in = in0 + (size_t)blockIdx.z * R * C;
  u16* out = out0 + (size_t)blockIdx.z * R * C;
  int tx = threadIdx.x & 31, ty = threadIdx.x >> 5;
  long r0 = blockIdx.y * 32, c0 = blockIdx.x * 32;
#pragma unroll
  for (int i = 0; i < 4; ++i)
    t[ty + i*8][tx] = in[(r0 + ty + i*8) * (long)C + c0 + tx];
  __syncthreads();
#pragma unroll
  for (int i = 0; i < 4; ++i)
    out[(c0 + ty + i*8) * (long)R + r0 + tx] = f2b(t[tx][ty + i*8]);
}

// ---------------- GEMM: C[M,N] = A[M,K] @ Bt[N,K]^T + bias ------------------
template<int EPI>
__global__ __launch_bounds__(256, 2)
void gemm_k(const u16* __restrict__ A, const u16* __restrict__ Bt,
            const float* __restrict__ bias,
            float* __restrict__ Cf, u16* __restrict__ Cb,
            const float* __restrict__ Res,
            int Ndim, int K, int scale_cols)
{
  __shared__ u16 As[128 * 32];
  __shared__ u16 Bs[128 * 32];
  const int tid = threadIdx.x;
  const int lane = tid & 63;
  const int wid = tid >> 6;
  const int wr = wid >> 1, wc = wid & 1;
  const int l15 = lane & 15, l4 = lane >> 4;
  const long arow0 = (long)blockIdx.x * 128;
  const long brow0 = (long)blockIdx.y * 128;

  f32x4 acc[4][4] = {};

  const int srow = tid >> 2;
  const int scol = (tid & 3) * 8;
  const u16* ga  = A  + (arow0 + srow) * K + scol;
  const u16* ga1 = ga + 64 * (long)K;
  const u16* gb  = Bt + (brow0 + srow) * K + scol;
  const u16* gb1 = gb + 64 * (long)K;
  u16* lA0 = &As[tid * 8];
  u16* lA1 = &As[2048 + tid * 8];
  u16* lB0 = &Bs[tid * 8];
  u16* lB1 = &Bs[2048 + tid * 8];

  for (int k0 = 0; k0 < K; k0 += 32) {
    gll16(ga + k0, lA0);
    gll16(ga1 + k0, lA1);
    gll16(gb + k0, lB0);
    gll16(gb1 + k0, lB1);
    __syncthreads();
    short8 af[4], bf[4];
#pragma unroll
    for (int m = 0; m < 4; ++m)
      af[m] = *(const short8*)&As[(wr*64 + m*16 + l15) * 32 + l4*8];
#pragma unroll
    for (int n = 0; n < 4; ++n)
      bf[n] = *(const short8*)&Bs[(wc*64 + n*16 + l15) * 32 + l4*8];
#pragma unroll
    for (int m = 0; m < 4; ++m)
#pragma unroll
      for (int n = 0; n < 4; ++n)
        acc[m][n] = __builtin_amdgcn_mfma_f32_16x16x32_bf16(af[m], bf[n], acc[m][n], 0, 0, 0);
    __syncthreads();
  }

  const int crow = wr*64 + l4*4;
  const int ccol = wc*64 + l15;
#pragma unroll
  for (int m = 0; m < 4; ++m) {
#pragma unroll
    for (int n = 0; n < 4; ++n) {
      const int col = (int)brow0 + ccol + n*16;
      const float bv = bias[col];
      const float sc = (EPI == 1 && col < scale_cols) ? SCALE_ : 1.0f;
#pragma unroll
      for (int r = 0; r < 4; ++r) {
        const long row = arow0 + crow + m*16 + r;
        float v = acc[m][n][r] + bv;
        if (EPI == 1) {
          Cb[row * Ndim + col] = f2b(v * sc);
        } else if (EPI == 0) {
          Cf[row * Ndim + col] = v;
          Cb[row * Ndim + col] = f2b(v);
        } else {
          Cf[row * Ndim + col] = v + Res[row * Ndim + col];
        }
      }
    }
  }
}

// ------------- flash attention v3: 32x32 MFMA, in-register softmax ----------
// grid: 512 blocks x 512 threads (8 waves x 32 q-rows = 256 q/block).
// Swapped QK^T (A=K,B=Q): C col=lane&31=q, row=(r&3)+8*(r>>2)+4*hi = kv.
// Softmax fully in-lane; P->bf16 PA fragments via cvt_pk + permlane32_swap.
__global__ __launch_bounds__(512)
void attn_k(const u16* __restrict__ qkv, u16* __restrict__ ob)
{
  __shared__ u16 Ks[2][4096];   // [64 kv][64 d], XOR-swizzled content
  __shared__ u16 Vs[2][4096];   // [64 d][64 kv] transposed, XOR-swizzled

  const int tid = threadIdx.x, lane = tid & 63, wid = tid >> 6;
  const int l31 = lane & 31, hi = lane >> 5;

  // XCD grouping: 4 q-tiles of a head on consecutive slots of one XCD.
  const int blk = blockIdx.x;
  const int xcd = blk & 7, slot = blk >> 3;
  const int bh = xcd + ((slot >> 2) << 3);   // head 0..127
  const int qx = slot & 3;                   // q-tile 0..3 (256 rows each)
  const int b = bh >> 4, nh = bh & 15;
  const int q0 = qx * 256 + wid * 32;

  const int RS = 3 * H_;
  const long base = (long)b * S_ * RS;
  const u16* Qg = qkv + base + nh * HD_;
  const u16* Kg = qkv + base + H_ + nh * HD_;
  const u16* Vg = qkv + base + 2 * H_ + nh * HD_;

  // Q B-fragments: lane holds Q[q0 + l31][ks*16 + hi*8 + j]  (pre-scaled)
  short8 qf[4];
#pragma unroll
  for (int ks = 0; ks < 4; ++ks)
    qf[ks] = *(const short8*)&Qg[(long)(q0 + l31) * RS + ks*16 + hi*8];

  float m_ = -1e30f, l_ = 0.f;
  f32x16 o0 = {}, o1 = {};

  // staging assignments
  const int krow = tid >> 3, kc = tid & 7;
  const int ksc = kc ^ (krow & 7);                       // pre-swizzled src col
  const long kgoff = (long)krow * RS + ksc * 8;
  const int vd = tid & 63, vch = tid >> 6;
  const int vbyt = (vd*128 + vch*16) ^ ((vd & 7) << 4);

  // ---- prologue: stage tile 0 ----
  {
    gll16(Kg + kgoff, (char*)&Ks[0][0] + tid*16);
    union { u16 u[8]; short8 v; } tv;
#pragma unroll
    for (int j = 0; j < 8; ++j)
      tv.u[j] = Vg[(long)(vch*8 + j) * RS + vd];
    *(short8*)((char*)&Vs[0][0] + vbyt) = tv.v;
  }
  __syncthreads();

  for (int t = 0; t < 16; ++t) {
    const int cur = t & 1, nxt = cur ^ 1;
    union { u16 u[8]; short8 v; } ta;
    if (t < 15) {
      const long kv1 = (long)(t + 1) * 64;
      gll16(Kg + kv1 * RS + kgoff, (char*)&Ks[nxt][0] + tid*16);
#pragma unroll
      for (int j = 0; j < 8; ++j)
        ta.u[j] = Vg[(kv1 + vch*8 + j) * RS + vd];
    }

    // ==== QK^T: S^T fragments s0 (kv 0-31), s1 (kv 32-63) ====
    f32x16 s0 = {}, s1 = {};
    __builtin_amdgcn_s_setprio(1);
#pragma unroll
    for (int ks = 0; ks < 4; ++ks) {
      const int koff = ks*32 + hi*16;
      const int by0 = (l31*128 + koff) ^ ((l31 & 7) << 4);
      short8 kf0 = *(const short8*)((const char*)&Ks[cur][0] + by0);
      s0 = __builtin_amdgcn_mfma_f32_32x32x16_bf16(kf0, qf[ks], s0, 0, 0, 0);
      const int by1 = ((32 + l31)*128 + koff) ^ ((l31 & 7) << 4);
      short8 kf1 = *(const short8*)((const char*)&Ks[cur][0] + by1);
      s1 = __builtin_amdgcn_mfma_f32_32x32x16_bf16(kf1, qf[ks], s1, 0, 0, 0);
    }
    __builtin_amdgcn_s_setprio(0);

    // ==== online softmax (in-lane; q = l31, kv rows split across hi) ====
    float tmax = -1e30f;
#pragma unroll
    for (int r = 0; r < 16; ++r) tmax = fmaxf(tmax, fmaxf(s0[r], s1[r]));
    tmax = fmaxf(tmax, __shfl_xor(tmax, 32));
    if (!__all(tmax <= m_ + 8.f)) {      // defer-max: rescale only on growth
      const float mnew = fmaxf(m_, tmax);
      const float corr = __expf(m_ - mnew);
      m_ = mnew; l_ *= corr;
#pragma unroll
      for (int r = 0; r < 16; ++r) {
        float cr = __shfl(corr, (r&3) + 8*(r>>2) + 4*hi);
        o0[r] *= cr; o1[r] *= cr;
      }
    }
    float sum = 0.f;
#pragma unroll
    for (int r = 0; r < 16; ++r) {
      float p0 = __expf(s0[r] - m_);
      float p1 = __expf(s1[r] - m_);
      s0[r] = p0; s1[r] = p1;
      sum += p0 + p1;
    }
    sum += __shfl_xor(sum, 32);
    l_ += sum;

    // ==== P -> bf16 PA fragments (cvt_pk + permlane32_swap) ====
    short8 pa[4];
#pragma unroll
    for (int ks2 = 0; ks2 < 2; ++ks2) {
      const int r0 = 8 * ks2;
      u32 A0 = cvtpk(s0[r0+0], s0[r0+1]), A1 = cvtpk(s0[r0+2], s0[r0+3]);
      u32 B0 = cvtpk(s0[r0+4], s0[r0+5]), B1 = cvtpk(s0[r0+6], s0[r0+7]);
      uint2v w02 = __builtin_amdgcn_permlane32_swap(A0, B0, false, false);
      uint2v w13 = __builtin_amdgcn_permlane32_swap(A1, B1, false, false);
      union { u32 w[4]; short8 v; } u_;
      u_.w[0] = w02.x; u_.w[1] = w13.x; u_.w[2] = w02.y; u_.w[3] = w13.y;
      pa[ks2] = u_.v;
    }
#pragma unroll
    for (int ks2 = 0; ks2 < 2; ++ks2) {
      const int r0 = 8 * ks2;
      u32 A0 = cvtpk(s1[r0+0], s1[r0+1]), A1 = cvtpk(s1[r0+2], s1[r0+3]);
      u32 B0 = cvtpk(s1[r0+4], s1[r0+5]), B1 = cvtpk(s1[r0+6], s1[r0+7]);
      uint2v w02 = __builtin_amdgcn_permlane32_swap(A0, B0, false, false);
      uint2v w13 = __builtin_amdgcn_permlane32_swap(A1, B1, false, false);
      union { u32 w[4]; short8 v; } u_;
      u_.w[0] = w02.x; u_.w[1] = w13.x; u_.w[2] = w02.y; u_.w[3] = w13.y;
      pa[2 + ks2] = u_.v;
    }

    // ==== O += P @ V  (B = V from transposed Vs, natural [k=kv][col=d]) ====
    __builtin_amdgcn_s_setprio(1);
#pragma unroll
    for (int ks = 0; ks < 4; ++ks) {
      const int vb = ks*32 + hi*16;
      const int by0 = (l31*128 + vb) ^ ((l31 & 7) << 4);
      short8 v0 = *(const short8*)((const char*)&Vs[cur][0] + by0);
      o0 = __builtin_amdgcn_mfma_f32_32x32x16_bf16(pa[ks], v0, o0, 0, 0, 0);
      const int by1 = ((32 + l31)*128 + vb) ^ ((l31 & 7) << 4);
      short8 v1 = *(const short8*)((const char*)&Vs[cur][0] + by1);
      o1 = __builtin_amdgcn_mfma_f32_32x32x16_bf16(pa[ks], v1, o1, 0, 0, 0);
    }
    __builtin_amdgcn_s_setprio(0);

    if (t < 15) {
      *(short8*)((char*)&Vs[nxt][0] + vbyt) = ta.v;
      __syncthreads();   // drains gll16 vmcnt -> Ks[nxt] valid; orders Vs[nxt]
    }
  }

  // ==== normalize and store: O row=(r&3)+8*(r>>2)+4*hi, col d = l31 (+32) ====
  const float linv = 1.0f / l_;
#pragma unroll
  for (int r = 0; r < 16; ++r) {
    const int rowq = (r&3) + 8*(r>>2) + 4*hi;
    const float li = __shfl(linv, rowq);
    const long srow = (long)(b * S_ + q0 + rowq);
    ob[srow * H_ + nh*HD_ + l31]      = f2b(o0[r] * li);
    ob[srow * H_ + nh*HD_ + 32 + l31] = f2b(o1[r] * li);
  }
}

// ---------------- LayerNorm over rows of H=1024 ----------------
__global__ __launch_bounds__(256)
void ln_k(const float* __restrict__ in, const float* __restrict__ g,
          const float* __restrict__ be, float* __restrict__ outf,
          u16* __restrict__ outb)
{
  const int row = blockIdx.x;
  const int tid = threadIdx.x;
  const float* x = in + (long)row * H_;
  f32x4 v = *(const f32x4*)&x[tid * 4];
  float s  = v[0] + v[1] + v[2] + v[3];
  float ss = v[0]*v[0] + v[1]*v[1] + v[2]*v[2] + v[3]*v[3];
#pragma unroll
  for (int o = 1; o < 64; o <<= 1) {
    s  += __shfl_xor(s, o);
    ss += __shfl_xor(ss, o);
  }
  __shared__ float rs[4], rq[4];
  const int wid = tid >> 6;
  if ((tid & 63) == 0) { rs[wid] = s; rq[wid] = ss; }
  __syncthreads();
  float ts = rs[0] + rs[1] + rs[2] + rs[3];
  float tq = rq[0] + rq[1] + rq[2] + rq[3];
  const float mu = ts * (1.0f / H_);
  const float var = tq * (1.0f / H_) - mu * mu;
  const float rstd = rsqrtf(var + EPS_);
  const long obase = (long)row * H_ + tid * 4;
#pragma unroll
  for (int j = 0; j < 4; ++j) {
    int c = tid * 4 + j;
    float y = (v[j] - mu) * rstd * g[c] + be[c];
    outf[obase + j] = y;
    if (outb) outb[obase + j] = f2b(y);
  }
}

// ---------------- mean-pool over S (partials + atomic) ----------------
__global__ void pool_k(const float* __restrict__ hf, float* __restrict__ pooled) {
  const int c = blockIdx.x * 256 + threadIdx.x;
  const int b = blockIdx.y;
  const int s0 = blockIdx.z * 128;
  float s = 0.f;
  for (int t = 0; t < 128; ++t) s += hf[((long)(b * S_ + s0 + t)) * H_ + c];
  atomicAdd(&pooled[b * H_ + c], s * (1.0f / S_));
}

// ---------------- small final GEMM (fp32) ----------------
__global__ void fgemm_k(const float* __restrict__ pooled, const float* __restrict__ W,
                        const float* __restrict__ bias, float* __restrict__ out) {
  const int n = blockIdx.x * 256 + threadIdx.x;
  const int b = blockIdx.y;
  float s = bias[n];
  for (int k = 0; k < H_; ++k) s += pooled[b * H_ + k] * W[(long)k * H_ + n];
  out[b * H_ + n] = s;
}

extern "C" void kernel_launch(void* const* d_in, const int* in_sizes, int n_in,
                              void* d_out, int out_size, void* d_ws, size_t ws_size,
                              hipStream_t stream) {
  const float* x     = (const float*)d_in[0];
  const float* W_in  = (const float*)d_in[1];
  const float* b_in  = (const float*)d_in[2];
  const float* W_qkv = (const float*)d_in[3];
  const float* b_qkv = (const float*)d_in[4];
  const float* W_o   = (const float*)d_in[5];
  const float* b_o   = (const float*)d_in[6];
  const float* g1    = (const float*)d_in[7];
  const float* be1   = (const float*)d_in[8];
  const float* W_out = (const float*)d_in[9];
  const float* b_out = (const float*)d_in[10];
  const float* g2    = (const float*)d_in[11];
  const float* be2   = (const float*)d_in[12];
  float* outp = (float*)d_out;

  char* ws = (char*)d_ws;
  float* hf    = (float*)(ws + 0);            // 33.55 MB
  u16*   hb    = (u16*)(ws + 33554432);       // 16.78 MB
  u16*   qkvb  = (u16*)(ws + 50331648);       // 50.33 MB
  float* resf  = (float*)(ws + 50331648);     // aliases qkvb (disjoint in time)
  u16*   ob    = (u16*)(ws + 100663296);      // 16.78 MB
  u16*   xb    = (u16*)(ws + 100663296);      // aliases ob (xb dead before attn)
  u16*   WinT  = (u16*)(ws + 117440512);      // 1.05 MB
  u16*   WqkvT = (u16*)(ws + 118489088);      // 25.17 MB
  u16*   WoT   = (u16*)(ws + 143654912);      // 8.39 MB
  float* pooled= (float*)(ws + 152043520);
  float* tmpf  = (float*)(ws + 152076288);

  // convert input + weights to bf16 (weights transposed to [N,K]), batched
  cvt_k<<<dim3(M_ * DIN_ / 1024), 256, 0, stream>>>(x, xb);
  tcvt_k<<<dim3(H_/32, DIN_/32, 1), 256, 0, stream>>>(W_in, WinT, DIN_, H_);
  tcvt_k<<<dim3(3*H_/32, H_/32, L_), 256, 0, stream>>>(W_qkv, WqkvT, H_, 3*H_);
  tcvt_k<<<dim3(H_/32, H_/32, L_), 256, 0, stream>>>(W_o, WoT, H_, H_);

  // h = x @ W_in + b_in   (fp32 + bf16 copies)
  gemm_k<0><<<dim3(M_/128, H_/128), 256, 0, stream>>>(xb, WinT, b_in, hf, hb, nullptr, H_, DIN_, 0);

  for (int l = 0; l < L_; ++l) {
    gemm_k<1><<<dim3(M_/128, 3*H_/128), 256, 0, stream>>>(hb, WqkvT + (size_t)l*3*H_*H_,
                                                          b_qkv + l*3*H_, nullptr, qkvb, nullptr,
                                                          3*H_, H_, H_);
    attn_k<<<dim3(512), 512, 0, stream>>>(qkvb, ob);
    gemm_k<2><<<dim3(M_/128, H_/128), 256, 0, stream>>>(ob, WoT + (size_t)l*H_*H_,
                                                        b_o + l*H_, resf, nullptr, hf,
                                                        H_, H_, 0);
    ln_k<<<dim3(M_), 256, 0, stream>>>(resf, g1 + l*H_, be1 + l*H_, hf, hb);
  }

  hipMemsetAsync(pooled, 0, B_ * H_ * sizeof(float), stream);
  pool_k<<<dim3(H_/256, B_, 8), 256, 0, stream>>>(hf, pooled);
  fgemm_k<<<dim3(H_/256, B_), 256, 0, stream>>>(pooled, W_out, b_out, tmpf);
  ln_k<<<dim3(B_), 256, 0, stream>>>(tmpf, g2, be2, outp, nullptr);
}

// Round 6
// 942.228 us; speedup vs baseline: 1.2491x; 1.0100x over previous
//
#include <hip/hip_runtime.h>
#include <stdint.h>

typedef unsigned short u16;
typedef unsigned int   u32;
typedef __attribute__((ext_vector_type(8))) short short8;
typedef __attribute__((ext_vector_type(4))) float f32x4;
typedef __attribute__((ext_vector_type(16))) float f32x16;
typedef __attribute__((ext_vector_type(2))) unsigned int uint2v;

#define B_   8
#define S_   1024
#define DIN_ 512
#define H_   1024
#define NH_  16
#define HD_  64
#define L_   4
#define M_   (B_*S_)
#define SCALE_ 0.125f
#define EPS_ 1e-5f

__device__ __forceinline__ u16 f2b(float f) {
  u32 u = __builtin_bit_cast(u32, f);
  u32 r = (u + 0x7fffu + ((u >> 16) & 1u)) >> 16;
  return (u16)r;
}

__device__ __forceinline__ u32 cvtpk(float lo, float hi) {
  u32 r;
  asm("v_cvt_pk_bf16_f32 %0, %1, %2" : "=v"(r) : "v"(lo), "v"(hi));
  return r;
}

__device__ __forceinline__ void gll16(const void* g, void* l) {
  __builtin_amdgcn_global_load_lds(
      (const __attribute__((address_space(1))) u32*)(uintptr_t)g,
      (__attribute__((address_space(3))) u32*)(uintptr_t)l,
      16, 0, 0);
}

// ---------------- fp32 -> bf16 flat convert (4 elems/thread) ----------------
__global__ void cvt_k(const float* __restrict__ in, u16* __restrict__ out) {
  long i = (long)(blockIdx.x * 256 + threadIdx.x) * 4;
  f32x4 v = *(const f32x4*)&in[i];
  u32 p0 = (u32)f2b(v[0]) | ((u32)f2b(v[1]) << 16);
  u32 p1 = (u32)f2b(v[2]) | ((u32)f2b(v[3]) << 16);
  u32* o = (u32*)&out[i];
  o[0] = p0; o[1] = p1;
}

// -------- fp32 [R,C] -> bf16 [C,R] transpose-convert, batched over z --------
__global__ __launch_bounds__(256)
void tcvt_k(const float* __restrict__ in0, u16* __restrict__ out0, int R, int C) {
  __shared__ float t[32][33];
  const float* in = in0 + (size_t)blockIdx.z * R * C;
  u16* out = out0 + (size_t)blockIdx.z * R * C;
  int tx = threadIdx.x & 31, ty = threadIdx.x >> 5;
  long r0 = blockIdx.y * 32, c0 = blockIdx.x * 32;
#pragma unroll
  for (int i = 0; i < 4; ++i)
    t[ty + i*8][tx] = in[(r0 + ty + i*8) * (long)C + c0 + tx];
  __syncthreads();
#pragma unroll
  for (int i = 0; i < 4; ++i)
    out[(c0 + ty + i*8) * (long)R + r0 + tx] = f2b(t[tx][ty + i*8]);
}

// ---------------- GEMM: C[M,N] = A[M,K] @ Bt[N,K]^T + bias ------------------
// Depth-2 prefetch pipeline: 3 LDS buffers, counted s_waitcnt vmcnt(8) + raw
// s_barrier (prefetch loads stay in flight across barriers - T4).
template<int EPI>
__global__ __launch_bounds__(256, 2)
void gemm_k(const u16* __restrict__ A, const u16* __restrict__ Bt,
            const float* __restrict__ bias,
            float* __restrict__ Cf, u16* __restrict__ Cb,
            const float* __restrict__ Res,
            int Ndim, int K, int scale_cols)
{
  __shared__ u16 As[3][128 * 32];
  __shared__ u16 Bs[3][128 * 32];
  const int tid = threadIdx.x;
  const int lane = tid & 63;
  const int wid = tid >> 6;
  const int wr = wid >> 1, wc = wid & 1;
  const int l15 = lane & 15, l4 = lane >> 4;
  const long arow0 = (long)blockIdx.x * 128;
  const long brow0 = (long)blockIdx.y * 128;

  f32x4 acc[4][4] = {};

  const int srow = tid >> 2;
  const int scol = (tid & 3) * 8;
  const u16* ga  = A  + (arow0 + srow) * K + scol;
  const u16* ga1 = ga + 64 * (long)K;
  const u16* gb  = Bt + (brow0 + srow) * K + scol;
  const u16* gb1 = gb + 64 * (long)K;

  auto STAGE = [&](int buf, int k0) {
    gll16(ga + k0,  &As[buf][tid * 8]);
    gll16(ga1 + k0, &As[buf][2048 + tid * 8]);
    gll16(gb + k0,  &Bs[buf][tid * 8]);
    gll16(gb1 + k0, &Bs[buf][2048 + tid * 8]);
  };
  auto COMPUTE = [&](int buf) {
    short8 af[4], bf[4];
#pragma unroll
    for (int m = 0; m < 4; ++m)
      af[m] = *(const short8*)&As[buf][(wr*64 + m*16 + l15) * 32 + l4*8];
#pragma unroll
    for (int n = 0; n < 4; ++n)
      bf[n] = *(const short8*)&Bs[buf][(wc*64 + n*16 + l15) * 32 + l4*8];
    __builtin_amdgcn_s_setprio(1);
#pragma unroll
    for (int m = 0; m < 4; ++m)
#pragma unroll
      for (int n = 0; n < 4; ++n)
        acc[m][n] = __builtin_amdgcn_mfma_f32_16x16x32_bf16(af[m], bf[n], acc[m][n], 0, 0, 0);
    __builtin_amdgcn_s_setprio(0);
  };

  const int nt = K >> 5;      // >= 16 for all call sites
  STAGE(0, 0);
  STAGE(1, 32);
  for (int t = 0; t < nt; ++t) {
    if (t + 2 < nt) {
      STAGE((t + 2) % 3, (t + 2) * 32);
      // wait for tile-t loads only; t+1/t+2 (8 loads) stay in flight
      asm volatile("s_waitcnt vmcnt(8)\n\ts_barrier" ::: "memory");
    } else if (t + 1 < nt) {
      asm volatile("s_waitcnt vmcnt(4)\n\ts_barrier" ::: "memory");
    } else {
      asm volatile("s_waitcnt vmcnt(0)\n\ts_barrier" ::: "memory");
    }
    COMPUTE(t % 3);
    if (t + 1 < nt)
      asm volatile("s_barrier" ::: "memory");   // all reads done before reuse
  }

  const int crow = wr*64 + l4*4;
  const int ccol = wc*64 + l15;
#pragma unroll
  for (int m = 0; m < 4; ++m) {
#pragma unroll
    for (int n = 0; n < 4; ++n) {
      const int col = (int)brow0 + ccol + n*16;
      const float bv = bias[col];
      const float sc = (EPI == 1 && col < scale_cols) ? SCALE_ : 1.0f;
#pragma unroll
      for (int r = 0; r < 4; ++r) {
        const long row = arow0 + crow + m*16 + r;
        float v = acc[m][n][r] + bv;
        if (EPI == 1) {
          Cb[row * Ndim + col] = f2b(v * sc);
        } else if (EPI == 0) {
          Cf[row * Ndim + col] = v;
          Cb[row * Ndim + col] = f2b(v);
        } else {
          Cf[row * Ndim + col] = v + Res[row * Ndim + col];
        }
      }
    }
  }
}

// ------------- flash attention v3: 32x32 MFMA, in-register softmax ----------
// grid: 512 blocks x 512 threads (8 waves x 32 q-rows = 256 q/block).
// Swapped QK^T (A=K,B=Q): C col=lane&31=q, row=(r&3)+8*(r>>2)+4*hi = kv.
// Softmax fully in-lane; P->bf16 PA fragments via cvt_pk + permlane32_swap.
__global__ __launch_bounds__(512)
void attn_k(const u16* __restrict__ qkv, u16* __restrict__ ob)
{
  __shared__ u16 Ks[2][4096];   // [64 kv][64 d], XOR-swizzled content
  __shared__ u16 Vs[2][4096];   // [64 d][64 kv] transposed, XOR-swizzled

  const int tid = threadIdx.x, lane = tid & 63, wid = tid >> 6;
  const int l31 = lane & 31, hi = lane >> 5;

  // XCD grouping: 4 q-tiles of a head on consecutive slots of one XCD.
  const int blk = blockIdx.x;
  const int xcd = blk & 7, slot = blk >> 3;
  const int bh = xcd + ((slot >> 2) << 3);   // head 0..127
  const int qx = slot & 3;                   // q-tile 0..3 (256 rows each)
  const int b = bh >> 4, nh = bh & 15;
  const int q0 = qx * 256 + wid * 32;

  const int RS = 3 * H_;
  const long base = (long)b * S_ * RS;
  const u16* Qg = qkv + base + nh * HD_;
  const u16* Kg = qkv + base + H_ + nh * HD_;
  const u16* Vg = qkv + base + 2 * H_ + nh * HD_;

  // Q B-fragments: lane holds Q[q0 + l31][ks*16 + hi*8 + j]  (pre-scaled)
  short8 qf[4];
#pragma unroll
  for (int ks = 0; ks < 4; ++ks)
    qf[ks] = *(const short8*)&Qg[(long)(q0 + l31) * RS + ks*16 + hi*8];

  float m_ = -1e30f, l_ = 0.f;
  f32x16 o0 = {}, o1 = {};

  // staging assignments
  const int krow = tid >> 3, kc = tid & 7;
  const int ksc = kc ^ (krow & 7);                       // pre-swizzled src col
  const long kgoff = (long)krow * RS + ksc * 8;
  const int vd = tid & 63, vch = tid >> 6;
  const int vbyt = (vd*128 + vch*16) ^ ((vd & 7) << 4);

  // ---- prologue: stage tile 0 ----
  {
    gll16(Kg + kgoff, (char*)&Ks[0][0] + tid*16);
    union { u16 u[8]; short8 v; } tv;
#pragma unroll
    for (int j = 0; j < 8; ++j)
      tv.u[j] = Vg[(long)(vch*8 + j) * RS + vd];
    *(short8*)((char*)&Vs[0][0] + vbyt) = tv.v;
  }
  __syncthreads();

  for (int t = 0; t < 16; ++t) {
    const int cur = t & 1, nxt = cur ^ 1;
    union { u16 u[8]; short8 v; } ta;
    if (t < 15) {
      const long kv1 = (long)(t + 1) * 64;
      gll16(Kg + kv1 * RS + kgoff, (char*)&Ks[nxt][0] + tid*16);
#pragma unroll
      for (int j = 0; j < 8; ++j)
        ta.u[j] = Vg[(kv1 + vch*8 + j) * RS + vd];
    }

    // ==== QK^T: S^T fragments s0 (kv 0-31), s1 (kv 32-63) ====
    f32x16 s0 = {}, s1 = {};
    __builtin_amdgcn_s_setprio(1);
#pragma unroll
    for (int ks = 0; ks < 4; ++ks) {
      const int koff = ks*32 + hi*16;
      const int by0 = (l31*128 + koff) ^ ((l31 & 7) << 4);
      short8 kf0 = *(const short8*)((const char*)&Ks[cur][0] + by0);
      s0 = __builtin_amdgcn_mfma_f32_32x32x16_bf16(kf0, qf[ks], s0, 0, 0, 0);
      const int by1 = ((32 + l31)*128 + koff) ^ ((l31 & 7) << 4);
      short8 kf1 = *(const short8*)((const char*)&Ks[cur][0] + by1);
      s1 = __builtin_amdgcn_mfma_f32_32x32x16_bf16(kf1, qf[ks], s1, 0, 0, 0);
    }
    __builtin_amdgcn_s_setprio(0);

    // ==== online softmax (in-lane; q = l31, kv rows split across hi) ====
    float tmax = -1e30f;
#pragma unroll
    for (int r = 0; r < 16; ++r) tmax = fmaxf(tmax, fmaxf(s0[r], s1[r]));
    tmax = fmaxf(tmax, __shfl_xor(tmax, 32));
    if (!__all(tmax <= m_ + 8.f)) {      // defer-max: rescale only on growth
      const float mnew = fmaxf(m_, tmax);
      const float corr = __expf(m_ - mnew);
      m_ = mnew; l_ *= corr;
#pragma unroll
      for (int r = 0; r < 16; ++r) {
        float cr = __shfl(corr, (r&3) + 8*(r>>2) + 4*hi);
        o0[r] *= cr; o1[r] *= cr;
      }
    }
    float sum = 0.f;
#pragma unroll
    for (int r = 0; r < 16; ++r) {
      float p0 = __expf(s0[r] - m_);
      float p1 = __expf(s1[r] - m_);
      s0[r] = p0; s1[r] = p1;
      sum += p0 + p1;
    }
    sum += __shfl_xor(sum, 32);
    l_ += sum;

    // ==== P -> bf16 PA fragments (cvt_pk + permlane32_swap) ====
    short8 pa[4];
#pragma unroll
    for (int ks2 = 0; ks2 < 2; ++ks2) {
      const int r0 = 8 * ks2;
      u32 A0 = cvtpk(s0[r0+0], s0[r0+1]), A1 = cvtpk(s0[r0+2], s0[r0+3]);
      u32 B0 = cvtpk(s0[r0+4], s0[r0+5]), B1 = cvtpk(s0[r0+6], s0[r0+7]);
      uint2v w02 = __builtin_amdgcn_permlane32_swap(A0, B0, false, false);
      uint2v w13 = __builtin_amdgcn_permlane32_swap(A1, B1, false, false);
      union { u32 w[4]; short8 v; } u_;
      u_.w[0] = w02.x; u_.w[1] = w13.x; u_.w[2] = w02.y; u_.w[3] = w13.y;
      pa[ks2] = u_.v;
    }
#pragma unroll
    for (int ks2 = 0; ks2 < 2; ++ks2) {
      const int r0 = 8 * ks2;
      u32 A0 = cvtpk(s1[r0+0], s1[r0+1]), A1 = cvtpk(s1[r0+2], s1[r0+3]);
      u32 B0 = cvtpk(s1[r0+4], s1[r0+5]), B1 = cvtpk(s1[r0+6], s1[r0+7]);
      uint2v w02 = __builtin_amdgcn_permlane32_swap(A0, B0, false, false);
      uint2v w13 = __builtin_amdgcn_permlane32_swap(A1, B1, false, false);
      union { u32 w[4]; short8 v; } u_;
      u_.w[0] = w02.x; u_.w[1] = w13.x; u_.w[2] = w02.y; u_.w[3] = w13.y;
      pa[2 + ks2] = u_.v;
    }

    // ==== O += P @ V  (B = V from transposed Vs, natural [k=kv][col=d]) ====
    __builtin_amdgcn_s_setprio(1);
#pragma unroll
    for (int ks = 0; ks < 4; ++ks) {
      const int vb = ks*32 + hi*16;
      const int by0 = (l31*128 + vb) ^ ((l31 & 7) << 4);
      short8 v0 = *(const short8*)((const char*)&Vs[cur][0] + by0);
      o0 = __builtin_amdgcn_mfma_f32_32x32x16_bf16(pa[ks], v0, o0, 0, 0, 0);
      const int by1 = ((32 + l31)*128 + vb) ^ ((l31 & 7) << 4);
      short8 v1 = *(const short8*)((const char*)&Vs[cur][0] + by1);
      o1 = __builtin_amdgcn_mfma_f32_32x32x16_bf16(pa[ks], v1, o1, 0, 0, 0);
    }
    __builtin_amdgcn_s_setprio(0);

    if (t < 15) {
      *(short8*)((char*)&Vs[nxt][0] + vbyt) = ta.v;
      __syncthreads();   // drains gll16 vmcnt -> Ks[nxt] valid; orders Vs[nxt]
    }
  }

  // ==== normalize and store: O row=(r&3)+8*(r>>2)+4*hi, col d = l31 (+32) ====
  const float linv = 1.0f / l_;
#pragma unroll
  for (int r = 0; r < 16; ++r) {
    const int rowq = (r&3) + 8*(r>>2) + 4*hi;
    const float li = __shfl(linv, rowq);
    const long srow = (long)(b * S_ + q0 + rowq);
    ob[srow * H_ + nh*HD_ + l31]      = f2b(o0[r] * li);
    ob[srow * H_ + nh*HD_ + 32 + l31] = f2b(o1[r] * li);
  }
}

// ---------------- LayerNorm over rows of H=1024 ----------------
__global__ __launch_bounds__(256)
void ln_k(const float* __restrict__ in, const float* __restrict__ g,
          const float* __restrict__ be, float* __restrict__ outf,
          u16* __restrict__ outb)
{
  const int row = blockIdx.x;
  const int tid = threadIdx.x;
  const float* x = in + (long)row * H_;
  f32x4 v = *(const f32x4*)&x[tid * 4];
  float s  = v[0] + v[1] + v[2] + v[3];
  float ss = v[0]*v[0] + v[1]*v[1] + v[2]*v[2] + v[3]*v[3];
#pragma unroll
  for (int o = 1; o < 64; o <<= 1) {
    s  += __shfl_xor(s, o);
    ss += __shfl_xor(ss, o);
  }
  __shared__ float rs[4], rq[4];
  const int wid = tid >> 6;
  if ((tid & 63) == 0) { rs[wid] = s; rq[wid] = ss; }
  __syncthreads();
  float ts = rs[0] + rs[1] + rs[2] + rs[3];
  float tq = rq[0] + rq[1] + rq[2] + rq[3];
  const float mu = ts * (1.0f / H_);
  const float var = tq * (1.0f / H_) - mu * mu;
  const float rstd = rsqrtf(var + EPS_);
  const long obase = (long)row * H_ + tid * 4;
#pragma unroll
  for (int j = 0; j < 4; ++j) {
    int c = tid * 4 + j;
    float y = (v[j] - mu) * rstd * g[c] + be[c];
    outf[obase + j] = y;
    if (outb) outb[obase + j] = f2b(y);
  }
}

// ---------------- mean-pool over S (partials + atomic) ----------------
__global__ void pool_k(const float* __restrict__ hf, float* __restrict__ pooled) {
  const int c = blockIdx.x * 256 + threadIdx.x;
  const int b = blockIdx.y;
  const int s0 = blockIdx.z * 128;
  float s = 0.f;
  for (int t = 0; t < 128; ++t) s += hf[((long)(b * S_ + s0 + t)) * H_ + c];
  atomicAdd(&pooled[b * H_ + c], s * (1.0f / S_));
}

// ---------------- small final GEMM (fp32) ----------------
__global__ void fgemm_k(const float* __restrict__ pooled, const float* __restrict__ W,
                        const float* __restrict__ bias, float* __restrict__ out) {
  const int n = blockIdx.x * 256 + threadIdx.x;
  const int b = blockIdx.y;
  float s = bias[n];
  for (int k = 0; k < H_; ++k) s += pooled[b * H_ + k] * W[(long)k * H_ + n];
  out[b * H_ + n] = s;
}

extern "C" void kernel_launch(void* const* d_in, const int* in_sizes, int n_in,
                              void* d_out, int out_size, void* d_ws, size_t ws_size,
                              hipStream_t stream) {
  const float* x     = (const float*)d_in[0];
  const float* W_in  = (const float*)d_in[1];
  const float* b_in  = (const float*)d_in[2];
  const float* W_qkv = (const float*)d_in[3];
  const float* b_qkv = (const float*)d_in[4];
  const float* W_o   = (const float*)d_in[5];
  const float* b_o   = (const float*)d_in[6];
  const float* g1    = (const float*)d_in[7];
  const float* be1   = (const float*)d_in[8];
  const float* W_out = (const float*)d_in[9];
  const float* b_out = (const float*)d_in[10];
  const float* g2    = (const float*)d_in[11];
  const float* be2   = (const float*)d_in[12];
  float* outp = (float*)d_out;

  char* ws = (char*)d_ws;
  float* hf    = (float*)(ws + 0);            // 33.55 MB
  u16*   hb    = (u16*)(ws + 33554432);       // 16.78 MB
  u16*   qkvb  = (u16*)(ws + 50331648);       // 50.33 MB
  float* resf  = (float*)(ws + 50331648);     // aliases qkvb (disjoint in time)
  u16*   ob    = (u16*)(ws + 100663296);      // 16.78 MB
  u16*   xb    = (u16*)(ws + 100663296);      // aliases ob (xb dead before attn)
  u16*   WinT  = (u16*)(ws + 117440512);      // 1.05 MB
  u16*   WqkvT = (u16*)(ws + 118489088);      // 25.17 MB
  u16*   WoT   = (u16*)(ws + 143654912);      // 8.39 MB
  float* pooled= (float*)(ws + 152043520);
  float* tmpf  = (float*)(ws + 152076288);

  // convert input + weights to bf16 (weights transposed to [N,K]), batched
  cvt_k<<<dim3(M_ * DIN_ / 1024), 256, 0, stream>>>(x, xb);
  tcvt_k<<<dim3(H_/32, DIN_/32, 1), 256, 0, stream>>>(W_in, WinT, DIN_, H_);
  tcvt_k<<<dim3(3*H_/32, H_/32, L_), 256, 0, stream>>>(W_qkv, WqkvT, H_, 3*H_);
  tcvt_k<<<dim3(H_/32, H_/32, L_), 256, 0, stream>>>(W_o, WoT, H_, H_);

  // h = x @ W_in + b_in   (fp32 + bf16 copies)
  gemm_k<0><<<dim3(M_/128, H_/128), 256, 0, stream>>>(xb, WinT, b_in, hf, hb, nullptr, H_, DIN_, 0);

  for (int l = 0; l < L_; ++l) {
    gemm_k<1><<<dim3(M_/128, 3*H_/128), 256, 0, stream>>>(hb, WqkvT + (size_t)l*3*H_*H_,
                                                          b_qkv + l*3*H_, nullptr, qkvb, nullptr,
                                                          3*H_, H_, H_);
    attn_k<<<dim3(512), 512, 0, stream>>>(qkvb, ob);
    gemm_k<2><<<dim3(M_/128, H_/128), 256, 0, stream>>>(ob, WoT + (size_t)l*H_*H_,
                                                        b_o + l*H_, resf, nullptr, hf,
                                                        H_, H_, 0);
    ln_k<<<dim3(M_), 256, 0, stream>>>(resf, g1 + l*H_, be1 + l*H_, hf, hb);
  }

  hipMemsetAsync(pooled, 0, B_ * H_ * sizeof(float), stream);
  pool_k<<<dim3(H_/256, B_, 8), 256, 0, stream>>>(hf, pooled);
  fgemm_k<<<dim3(H_/256, B_), 256, 0, stream>>>(pooled, W_out, b_out, tmpf);
  ln_k<<<dim3(B_), 256, 0, stream>>>(tmpf, g2, be2, outp, nullptr);
}

// Round 7
// 935.386 us; speedup vs baseline: 1.2583x; 1.0073x over previous
//
#include <hip/hip_runtime.h>
#include <stdint.h>

typedef unsigned short u16;
typedef unsigned int   u32;
typedef __attribute__((ext_vector_type(8))) short short8;
typedef __attribute__((ext_vector_type(4))) float f32x4;
typedef __attribute__((ext_vector_type(16))) float f32x16;
typedef __attribute__((ext_vector_type(2))) unsigned int uint2v;

#define B_   8
#define S_   1024
#define DIN_ 512
#define H_   1024
#define NH_  16
#define HD_  64
#define L_   4
#define M_   (B_*S_)
#define SCALE_ 0.125f
#define EPS_ 1e-5f

__device__ __forceinline__ u16 f2b(float f) {
  u32 u = __builtin_bit_cast(u32, f);
  u32 r = (u + 0x7fffu + ((u >> 16) & 1u)) >> 16;
  return (u16)r;
}

__device__ __forceinline__ u32 cvtpk(float lo, float hi) {
  u32 r;
  asm("v_cvt_pk_bf16_f32 %0, %1, %2" : "=v"(r) : "v"(lo), "v"(hi));
  return r;
}

__device__ __forceinline__ void gll16(const void* g, void* l) {
  __builtin_amdgcn_global_load_lds(
      (const __attribute__((address_space(1))) u32*)(uintptr_t)g,
      (__attribute__((address_space(3))) u32*)(uintptr_t)l,
      16, 0, 0);
}

// ---------------- fp32 -> bf16 flat convert (4 elems/thread) ----------------
__global__ void cvt_k(const float* __restrict__ in, u16* __restrict__ out) {
  long i = (long)(blockIdx.x * 256 + threadIdx.x) * 4;
  f32x4 v = *(const f32x4*)&in[i];
  u32 p0 = (u32)f2b(v[0]) | ((u32)f2b(v[1]) << 16);
  u32 p1 = (u32)f2b(v[2]) | ((u32)f2b(v[3]) << 16);
  u32* o = (u32*)&out[i];
  o[0] = p0; o[1] = p1;
}

// -------- fp32 [R,C] -> bf16 [C,R] transpose-convert, batched over z --------
__global__ __launch_bounds__(256)
void tcvt_k(const float* __restrict__ in0, u16* __restrict__ out0, int R, int C) {
  __shared__ float t[32][33];
  const float* in = in0 + (size_t)blockIdx.z * R * C;
  u16* out = out0 + (size_t)blockIdx.z * R * C;
  int tx = threadIdx.x & 31, ty = threadIdx.x >> 5;
  long r0 = blockIdx.y * 32, c0 = blockIdx.x * 32;
#pragma unroll
  for (int i = 0; i < 4; ++i)
    t[ty + i*8][tx] = in[(r0 + ty + i*8) * (long)C + c0 + tx];
  __syncthreads();
#pragma unroll
  for (int i = 0; i < 4; ++i)
    out[(c0 + ty + i*8) * (long)R + r0 + tx] = f2b(t[tx][ty + i*8]);
}

// ---------------- 128x128 GEMM (in-proj / O-proj): simple 2-barrier --------
template<int EPI>
__global__ __launch_bounds__(256, 2)
void gemm_k(const u16* __restrict__ A, const u16* __restrict__ Bt,
            const float* __restrict__ bias,
            float* __restrict__ Cf, u16* __restrict__ Cb,
            const float* __restrict__ Res,
            int Ndim, int K, int scale_cols)
{
  __shared__ u16 As[128 * 32];
  __shared__ u16 Bs[128 * 32];
  const int tid = threadIdx.x;
  const int lane = tid & 63;
  const int wid = tid >> 6;
  const int wr = wid >> 1, wc = wid & 1;
  const int l15 = lane & 15, l4 = lane >> 4;
  const long arow0 = (long)blockIdx.x * 128;
  const long brow0 = (long)blockIdx.y * 128;

  f32x4 acc[4][4] = {};

  const int srow = tid >> 2;
  const int scol = (tid & 3) * 8;
  const u16* ga  = A  + (arow0 + srow) * K + scol;
  const u16* ga1 = ga + 64 * (long)K;
  const u16* gb  = Bt + (brow0 + srow) * K + scol;
  const u16* gb1 = gb + 64 * (long)K;
  u16* lA0 = &As[tid * 8];
  u16* lA1 = &As[2048 + tid * 8];
  u16* lB0 = &Bs[tid * 8];
  u16* lB1 = &Bs[2048 + tid * 8];

  for (int k0 = 0; k0 < K; k0 += 32) {
    gll16(ga + k0, lA0);
    gll16(ga1 + k0, lA1);
    gll16(gb + k0, lB0);
    gll16(gb1 + k0, lB1);
    __syncthreads();
    short8 af[4], bf[4];
#pragma unroll
    for (int m = 0; m < 4; ++m)
      af[m] = *(const short8*)&As[(wr*64 + m*16 + l15) * 32 + l4*8];
#pragma unroll
    for (int n = 0; n < 4; ++n)
      bf[n] = *(const short8*)&Bs[(wc*64 + n*16 + l15) * 32 + l4*8];
#pragma unroll
    for (int m = 0; m < 4; ++m)
#pragma unroll
      for (int n = 0; n < 4; ++n)
        acc[m][n] = __builtin_amdgcn_mfma_f32_16x16x32_bf16(af[m], bf[n], acc[m][n], 0, 0, 0);
    __syncthreads();
  }

  const int crow = wr*64 + l4*4;
  const int ccol = wc*64 + l15;
#pragma unroll
  for (int m = 0; m < 4; ++m) {
#pragma unroll
    for (int n = 0; n < 4; ++n) {
      const int col = (int)brow0 + ccol + n*16;
      const float bv = bias[col];
      const float sc = (EPI == 1 && col < scale_cols) ? SCALE_ : 1.0f;
#pragma unroll
      for (int r = 0; r < 4; ++r) {
        const long row = arow0 + crow + m*16 + r;
        float v = acc[m][n][r] + bv;
        if (EPI == 1) {
          Cb[row * Ndim + col] = f2b(v * sc);
        } else if (EPI == 0) {
          Cf[row * Ndim + col] = v;
          Cb[row * Ndim + col] = f2b(v);
        } else {
          Cf[row * Ndim + col] = v + Res[row * Ndim + col];
        }
      }
    }
  }
}

// ---------------- 256x256 8-phase GEMM for QKV (M=8192,N=3072,K=1024) -------
// 8 waves (2M x 4N), BK=64, 128KB LDS: [buf][A/B][half 128 rows][64 k] bf16,
// XOR-swizzled (byte ^= (row&7)<<4) via pre-swizzled global source (both-sides).
// Per K-tile: 4 phases x 16 MFMA (m-quadrants); B-frags read at quadrant 0.
// Staging stream p1..p8: A(2i+1)x2, B(2i+2)x2, A(2i+2)x2, B(2i+3)x2 - each
// half staged strictly after its slot's last reader. vmcnt(4) at p4/p8 only.
__global__ __launch_bounds__(512, 1)
void gemm8_k(const u16* __restrict__ A, const u16* __restrict__ Bt,
             const float* __restrict__ bias, u16* __restrict__ Cb)
{
  constexpr int K = 1024, N = 3 * H_;
  constexpr int NT = K / 64;                 // 16 K-tiles
  __shared__ u16 lds[8][8192];               // [buf*4 + op*2 + half][128*64]

  const int tid = threadIdx.x;
  const int lane = tid & 63;
  const int wid = tid >> 6;
  const int wm = wid >> 2, wn = wid & 3;
  const int l15 = lane & 15, l4 = lane >> 4;

  const int bid = blockIdx.x;                // 384 blocks; 384 % 8 == 0
  const int swz = (bid & 7) * 48 + (bid >> 3);
  const long arow0 = (long)(swz & 31) * 256;
  const long brow0 = (long)(swz >> 5) * 256;

  f32x4 acc[8][4] = {};
  short8 bfr[4][2];
  short8 afr[2][2];

  auto stage = [&](int buf, int op, int half, int kt) {
    const u16* src = op ? Bt : A;
    const long rb = (op ? brow0 : arow0) + half * 128;
    u16* dst = lds[buf*4 + op*2 + half];
#pragma unroll
    for (int ld = 0; ld < 2; ++ld) {
      int p = ld * 512 + tid;
      int row = p >> 3;
      int kc = (p & 7) ^ (row & 7);          // inverse swizzle on source
      gll16(src + (rb + row) * (long)K + kt * 64 + kc * 8, (char*)dst + p * 16);
    }
  };
  auto readB = [&](int buf) {
    const char* base = (const char*)lds[buf*4 + 2 + (wn >> 1)];
#pragma unroll
    for (int n = 0; n < 4; ++n)
#pragma unroll
      for (int ks = 0; ks < 2; ++ks) {
        int rh = (wn & 1) * 64 + n * 16 + l15;
        int byt = rh * 128 + ((((ks*4 + l4) * 16)) ^ ((rh & 7) << 4));
        bfr[n][ks] = *(const short8*)(base + byt);
      }
  };
  auto readA = [&](int buf, int q) {
    const char* base = (const char*)lds[buf*4 + wm];
#pragma unroll
    for (int j = 0; j < 2; ++j)
#pragma unroll
      for (int ks = 0; ks < 2; ++ks) {
        int rh = (2*q + j) * 16 + l15;
        int byt = rh * 128 + ((((ks*4 + l4) * 16)) ^ ((rh & 7) << 4));
        afr[j][ks] = *(const short8*)(base + byt);
      }
  };
  auto mm = [&](int q) {
    __builtin_amdgcn_s_setprio(1);
#pragma unroll
    for (int j = 0; j < 2; ++j)
#pragma unroll
      for (int n = 0; n < 4; ++n)
#pragma unroll
        for (int ks = 0; ks < 2; ++ks)
          acc[2*q+j][n] = __builtin_amdgcn_mfma_f32_16x16x32_bf16(
              afr[j][ks], bfr[n][ks], acc[2*q+j][n], 0, 0, 0);
    __builtin_amdgcn_s_setprio(0);
  };

#define PH(bufc, q, doB, sb, so, sh, st, doV)                     \
    readA(bufc, q); if (doB) readB(bufc);                         \
    stage(sb, so, sh, st);                                        \
    __builtin_amdgcn_s_barrier();                                 \
    asm volatile("s_waitcnt lgkmcnt(0)" ::: "memory");            \
    __builtin_amdgcn_sched_barrier(0);                            \
    mm(q);                                                        \
    if (doV) asm volatile("s_waitcnt vmcnt(4)" ::: "memory");     \
    __builtin_amdgcn_s_barrier();

  // prologue: tile0 all halves -> buf0; tile1 B halves -> buf1 (12 loads)
  stage(0,0,0,0); stage(0,0,1,0); stage(0,1,0,0); stage(0,1,1,0);
  stage(1,1,0,1); stage(1,1,1,1);
  asm volatile("s_waitcnt vmcnt(4)" ::: "memory");   // tile0 landed
  __builtin_amdgcn_s_barrier();

  const int niter = NT / 2;
  for (int i = 0; i < niter; ++i) {
    const int t1 = 2*i + 1;
    const int t2 = (2*i + 2 < NT) ? 2*i + 2 : NT - 1;   // clamped dummy stages
    const int t3 = (2*i + 3 < NT) ? 2*i + 3 : NT - 1;   // keep vmcnt counts
    PH(0, 0, true , 1, 0, 0, t1, false)   // compute tile 2i   q0, stage A0(2i+1)
    PH(0, 1, false, 1, 0, 1, t1, false)   //                   q1, stage A1(2i+1)
    PH(0, 2, false, 0, 1, 0, t2, false)   //                   q2, stage B0(2i+2)
    PH(0, 3, false, 0, 1, 1, t2, true )   //                   q3, stage B1(2i+2)
    PH(1, 0, true , 0, 0, 0, t2, false)   // compute tile 2i+1 q0, stage A0(2i+2)
    PH(1, 1, false, 0, 0, 1, t2, false)   //                   q1, stage A1(2i+2)
    PH(1, 2, false, 1, 1, 0, t3, false)   //                   q2, stage B0(2i+3)
    PH(1, 3, false, 1, 1, 1, t3, true )   //                   q3, stage B1(2i+3)
  }
#undef PH

  // epilogue: C row = arow0 + wm*128 + m*16 + l4*4 + r, col = brow0 + wn*64 + n*16 + l15
  const long crow0 = arow0 + wm * 128;
  const int  ccol0 = (int)brow0 + wn * 64;
#pragma unroll
  for (int m = 0; m < 8; ++m) {
#pragma unroll
    for (int n = 0; n < 4; ++n) {
      const int col = ccol0 + n * 16 + l15;
      const float bv = bias[col];
      const float sc = (col < H_) ? SCALE_ : 1.0f;
#pragma unroll
      for (int r = 0; r < 4; ++r) {
        const long row = crow0 + m * 16 + l4 * 4 + r;
        Cb[row * N + col] = f2b((acc[m][n][r] + bv) * sc);
      }
    }
  }
}

// ------------- flash attention v3: 32x32 MFMA, in-register softmax ----------
__global__ __launch_bounds__(512)
void attn_k(const u16* __restrict__ qkv, u16* __restrict__ ob)
{
  __shared__ u16 Ks[2][4096];   // [64 kv][64 d], XOR-swizzled content
  __shared__ u16 Vs[2][4096];   // [64 d][64 kv] transposed, XOR-swizzled

  const int tid = threadIdx.x, lane = tid & 63, wid = tid >> 6;
  const int l31 = lane & 31, hi = lane >> 5;

  const int blk = blockIdx.x;
  const int xcd = blk & 7, slot = blk >> 3;
  const int bh = xcd + ((slot >> 2) << 3);   // head 0..127
  const int qx = slot & 3;                   // q-tile 0..3 (256 rows each)
  const int b = bh >> 4, nh = bh & 15;
  const int q0 = qx * 256 + wid * 32;

  const int RS = 3 * H_;
  const long base = (long)b * S_ * RS;
  const u16* Qg = qkv + base + nh * HD_;
  const u16* Kg = qkv + base + H_ + nh * HD_;
  const u16* Vg = qkv + base + 2 * H_ + nh * HD_;

  short8 qf[4];
#pragma unroll
  for (int ks = 0; ks < 4; ++ks)
    qf[ks] = *(const short8*)&Qg[(long)(q0 + l31) * RS + ks*16 + hi*8];

  float m_ = -1e30f, l_ = 0.f;
  f32x16 o0 = {}, o1 = {};

  const int krow = tid >> 3, kc = tid & 7;
  const int ksc = kc ^ (krow & 7);
  const long kgoff = (long)krow * RS + ksc * 8;
  const int vd = tid & 63, vch = tid >> 6;
  const int vbyt = (vd*128 + vch*16) ^ ((vd & 7) << 4);

  {
    gll16(Kg + kgoff, (char*)&Ks[0][0] + tid*16);
    union { u16 u[8]; short8 v; } tv;
#pragma unroll
    for (int j = 0; j < 8; ++j)
      tv.u[j] = Vg[(long)(vch*8 + j) * RS + vd];
    *(short8*)((char*)&Vs[0][0] + vbyt) = tv.v;
  }
  __syncthreads();

  for (int t = 0; t < 16; ++t) {
    const int cur = t & 1, nxt = cur ^ 1;
    union { u16 u[8]; short8 v; } ta;
    if (t < 15) {
      const long kv1 = (long)(t + 1) * 64;
      gll16(Kg + kv1 * RS + kgoff, (char*)&Ks[nxt][0] + tid*16);
#pragma unroll
      for (int j = 0; j < 8; ++j)
        ta.u[j] = Vg[(kv1 + vch*8 + j) * RS + vd];
    }

    f32x16 s0 = {}, s1 = {};
    __builtin_amdgcn_s_setprio(1);
#pragma unroll
    for (int ks = 0; ks < 4; ++ks) {
      const int koff = ks*32 + hi*16;
      const int by0 = (l31*128 + koff) ^ ((l31 & 7) << 4);
      short8 kf0 = *(const short8*)((const char*)&Ks[cur][0] + by0);
      s0 = __builtin_amdgcn_mfma_f32_32x32x16_bf16(kf0, qf[ks], s0, 0, 0, 0);
      const int by1 = ((32 + l31)*128 + koff) ^ ((l31 & 7) << 4);
      short8 kf1 = *(const short8*)((const char*)&Ks[cur][0] + by1);
      s1 = __builtin_amdgcn_mfma_f32_32x32x16_bf16(kf1, qf[ks], s1, 0, 0, 0);
    }
    __builtin_amdgcn_s_setprio(0);

    float tmax = -1e30f;
#pragma unroll
    for (int r = 0; r < 16; ++r) tmax = fmaxf(tmax, fmaxf(s0[r], s1[r]));
    tmax = fmaxf(tmax, __shfl_xor(tmax, 32));
    if (!__all(tmax <= m_ + 8.f)) {
      const float mnew = fmaxf(m_, tmax);
      const float corr = __expf(m_ - mnew);
      m_ = mnew; l_ *= corr;
#pragma unroll
      for (int r = 0; r < 16; ++r) {
        float cr = __shfl(corr, (r&3) + 8*(r>>2) + 4*hi);
        o0[r] *= cr; o1[r] *= cr;
      }
    }
    float sum = 0.f;
#pragma unroll
    for (int r = 0; r < 16; ++r) {
      float p0 = __expf(s0[r] - m_);
      float p1 = __expf(s1[r] - m_);
      s0[r] = p0; s1[r] = p1;
      sum += p0 + p1;
    }
    sum += __shfl_xor(sum, 32);
    l_ += sum;

    short8 pa[4];
#pragma unroll
    for (int ks2 = 0; ks2 < 2; ++ks2) {
      const int r0 = 8 * ks2;
      u32 A0 = cvtpk(s0[r0+0], s0[r0+1]), A1 = cvtpk(s0[r0+2], s0[r0+3]);
      u32 B0 = cvtpk(s0[r0+4], s0[r0+5]), B1 = cvtpk(s0[r0+6], s0[r0+7]);
      uint2v w02 = __builtin_amdgcn_permlane32_swap(A0, B0, false, false);
      uint2v w13 = __builtin_amdgcn_permlane32_swap(A1, B1, false, false);
      union { u32 w[4]; short8 v; } u_;
      u_.w[0] = w02.x; u_.w[1] = w13.x; u_.w[2] = w02.y; u_.w[3] = w13.y;
      pa[ks2] = u_.v;
    }
#pragma unroll
    for (int ks2 = 0; ks2 < 2; ++ks2) {
      const int r0 = 8 * ks2;
      u32 A0 = cvtpk(s1[r0+0], s1[r0+1]), A1 = cvtpk(s1[r0+2], s1[r0+3]);
      u32 B0 = cvtpk(s1[r0+4], s1[r0+5]), B1 = cvtpk(s1[r0+6], s1[r0+7]);
      uint2v w02 = __builtin_amdgcn_permlane32_swap(A0, B0, false, false);
      uint2v w13 = __builtin_amdgcn_permlane32_swap(A1, B1, false, false);
      union { u32 w[4]; short8 v; } u_;
      u_.w[0] = w02.x; u_.w[1] = w13.x; u_.w[2] = w02.y; u_.w[3] = w13.y;
      pa[2 + ks2] = u_.v;
    }

    __builtin_amdgcn_s_setprio(1);
#pragma unroll
    for (int ks = 0; ks < 4; ++ks) {
      const int vb = ks*32 + hi*16;
      const int by0 = (l31*128 + vb) ^ ((l31 & 7) << 4);
      short8 v0 = *(const short8*)((const char*)&Vs[cur][0] + by0);
      o0 = __builtin_amdgcn_mfma_f32_32x32x16_bf16(pa[ks], v0, o0, 0, 0, 0);
      const int by1 = ((32 + l31)*128 + vb) ^ ((l31 & 7) << 4);
      short8 v1 = *(const short8*)((const char*)&Vs[cur][0] + by1);
      o1 = __builtin_amdgcn_mfma_f32_32x32x16_bf16(pa[ks], v1, o1, 0, 0, 0);
    }
    __builtin_amdgcn_s_setprio(0);

    if (t < 15) {
      *(short8*)((char*)&Vs[nxt][0] + vbyt) = ta.v;
      __syncthreads();
    }
  }

  const float linv = 1.0f / l_;
#pragma unroll
  for (int r = 0; r < 16; ++r) {
    const int rowq = (r&3) + 8*(r>>2) + 4*hi;
    const float li = __shfl(linv, rowq);
    const long srow = (long)(b * S_ + q0 + rowq);
    ob[srow * H_ + nh*HD_ + l31]      = f2b(o0[r] * li);
    ob[srow * H_ + nh*HD_ + 32 + l31] = f2b(o1[r] * li);
  }
}

// ---------------- LayerNorm over rows of H=1024 ----------------
__global__ __launch_bounds__(256)
void ln_k(const float* __restrict__ in, const float* __restrict__ g,
          const float* __restrict__ be, float* __restrict__ outf,
          u16* __restrict__ outb)
{
  const int row = blockIdx.x;
  const int tid = threadIdx.x;
  const float* x = in + (long)row * H_;
  f32x4 v = *(const f32x4*)&x[tid * 4];
  float s  = v[0] + v[1] + v[2] + v[3];
  float ss = v[0]*v[0] + v[1]*v[1] + v[2]*v[2] + v[3]*v[3];
#pragma unroll
  for (int o = 1; o < 64; o <<= 1) {
    s  += __shfl_xor(s, o);
    ss += __shfl_xor(ss, o);
  }
  __shared__ float rs[4], rq[4];
  const int wid = tid >> 6;
  if ((tid & 63) == 0) { rs[wid] = s; rq[wid] = ss; }
  __syncthreads();
  float ts = rs[0] + rs[1] + rs[2] + rs[3];
  float tq = rq[0] + rq[1] + rq[2] + rq[3];
  const float mu = ts * (1.0f / H_);
  const float var = tq * (1.0f / H_) - mu * mu;
  const float rstd = rsqrtf(var + EPS_);
  const long obase = (long)row * H_ + tid * 4;
#pragma unroll
  for (int j = 0; j < 4; ++j) {
    int c = tid * 4 + j;
    float y = (v[j] - mu) * rstd * g[c] + be[c];
    outf[obase + j] = y;
    if (outb) outb[obase + j] = f2b(y);
  }
}

// ---------------- mean-pool over S (partials + atomic) ----------------
__global__ void pool_k(const float* __restrict__ hf, float* __restrict__ pooled) {
  const int c = blockIdx.x * 256 + threadIdx.x;
  const int b = blockIdx.y;
  const int s0 = blockIdx.z * 128;
  float s = 0.f;
  for (int t = 0; t < 128; ++t) s += hf[((long)(b * S_ + s0 + t)) * H_ + c];
  atomicAdd(&pooled[b * H_ + c], s * (1.0f / S_));
}

// ---------------- small final GEMM (fp32) ----------------
__global__ void fgemm_k(const float* __restrict__ pooled, const float* __restrict__ W,
                        const float* __restrict__ bias, float* __restrict__ out) {
  const int n = blockIdx.x * 256 + threadIdx.x;
  const int b = blockIdx.y;
  float s = bias[n];
  for (int k = 0; k < H_; ++k) s += pooled[b * H_ + k] * W[(long)k * H_ + n];
  out[b * H_ + n] = s;
}

extern "C" void kernel_launch(void* const* d_in, const int* in_sizes, int n_in,
                              void* d_out, int out_size, void* d_ws, size_t ws_size,
                              hipStream_t stream) {
  const float* x     = (const float*)d_in[0];
  const float* W_in  = (const float*)d_in[1];
  const float* b_in  = (const float*)d_in[2];
  const float* W_qkv = (const float*)d_in[3];
  const float* b_qkv = (const float*)d_in[4];
  const float* W_o   = (const float*)d_in[5];
  const float* b_o   = (const float*)d_in[6];
  const float* g1    = (const float*)d_in[7];
  const float* be1   = (const float*)d_in[8];
  const float* W_out = (const float*)d_in[9];
  const float* b_out = (const float*)d_in[10];
  const float* g2    = (const float*)d_in[11];
  const float* be2   = (const float*)d_in[12];
  float* outp = (float*)d_out;

  char* ws = (char*)d_ws;
  float* hf    = (float*)(ws + 0);            // 33.55 MB
  u16*   hb    = (u16*)(ws + 33554432);       // 16.78 MB
  u16*   qkvb  = (u16*)(ws + 50331648);       // 50.33 MB
  float* resf  = (float*)(ws + 50331648);     // aliases qkvb (disjoint in time)
  u16*   ob    = (u16*)(ws + 100663296);      // 16.78 MB
  u16*   xb    = (u16*)(ws + 100663296);      // aliases ob (xb dead before attn)
  u16*   WinT  = (u16*)(ws + 117440512);      // 1.05 MB
  u16*   WqkvT = (u16*)(ws + 118489088);      // 25.17 MB
  u16*   WoT   = (u16*)(ws + 143654912);      // 8.39 MB
  float* pooled= (float*)(ws + 152043520);
  float* tmpf  = (float*)(ws + 152076288);

  cvt_k<<<dim3(M_ * DIN_ / 1024), 256, 0, stream>>>(x, xb);
  tcvt_k<<<dim3(H_/32, DIN_/32, 1), 256, 0, stream>>>(W_in, WinT, DIN_, H_);
  tcvt_k<<<dim3(3*H_/32, H_/32, L_), 256, 0, stream>>>(W_qkv, WqkvT, H_, 3*H_);
  tcvt_k<<<dim3(H_/32, H_/32, L_), 256, 0, stream>>>(W_o, WoT, H_, H_);

  gemm_k<0><<<dim3(M_/128, H_/128), 256, 0, stream>>>(xb, WinT, b_in, hf, hb, nullptr, H_, DIN_, 0);

  for (int l = 0; l < L_; ++l) {
    gemm8_k<<<dim3((M_/256) * (3*H_/256)), 512, 0, stream>>>(hb, WqkvT + (size_t)l*3*H_*H_,
                                                             b_qkv + l*3*H_, qkvb);
    attn_k<<<dim3(512), 512, 0, stream>>>(qkvb, ob);
    gemm_k<2><<<dim3(M_/128, H_/128), 256, 0, stream>>>(ob, WoT + (size_t)l*H_*H_,
                                                        b_o + l*H_, resf, nullptr, hf,
                                                        H_, H_, 0);
    ln_k<<<dim3(M_), 256, 0, stream>>>(resf, g1 + l*H_, be1 + l*H_, hf, hb);
  }

  hipMemsetAsync(pooled, 0, B_ * H_ * sizeof(float), stream);
  pool_k<<<dim3(H_/256, B_, 8), 256, 0, stream>>>(hf, pooled);
  fgemm_k<<<dim3(H_/256, B_), 256, 0, stream>>>(pooled, W_out, b_out, tmpf);
  ln_k<<<dim3(B_), 256, 0, stream>>>(tmpf, g2, be2, outp, nullptr);
}

// Round 8
// 876.843 us; speedup vs baseline: 1.3423x; 1.0668x over previous
//
#include <hip/hip_runtime.h>
#include <stdint.h>

typedef unsigned short u16;
typedef unsigned int   u32;
typedef __attribute__((ext_vector_type(8))) short short8;
typedef __attribute__((ext_vector_type(4))) float f32x4;
typedef __attribute__((ext_vector_type(16))) float f32x16;
typedef __attribute__((ext_vector_type(2))) unsigned int uint2v;

#define B_   8
#define S_   1024
#define DIN_ 512
#define H_   1024
#define NH_  16
#define HD_  64
#define L_   4
#define M_   (B_*S_)
#define SCALE_ 0.125f
#define EPS_ 1e-5f

__device__ __forceinline__ u16 f2b(float f) {
  u32 u = __builtin_bit_cast(u32, f);
  u32 r = (u + 0x7fffu + ((u >> 16) & 1u)) >> 16;
  return (u16)r;
}

__device__ __forceinline__ u32 cvtpk(float lo, float hi) {
  u32 r;
  asm("v_cvt_pk_bf16_f32 %0, %1, %2" : "=v"(r) : "v"(lo), "v"(hi));
  return r;
}

__device__ __forceinline__ void gll16(const void* g, void* l) {
  __builtin_amdgcn_global_load_lds(
      (const __attribute__((address_space(1))) u32*)(uintptr_t)g,
      (__attribute__((address_space(3))) u32*)(uintptr_t)l,
      16, 0, 0);
}

// ---------------- fp32 -> bf16 flat convert (4 elems/thread) ----------------
__global__ void cvt_k(const float* __restrict__ in, u16* __restrict__ out) {
  long i = (long)(blockIdx.x * 256 + threadIdx.x) * 4;
  f32x4 v = *(const f32x4*)&in[i];
  u32 p0 = (u32)f2b(v[0]) | ((u32)f2b(v[1]) << 16);
  u32 p1 = (u32)f2b(v[2]) | ((u32)f2b(v[3]) << 16);
  u32* o = (u32*)&out[i];
  o[0] = p0; o[1] = p1;
}

// -------- fp32 [R,C] -> bf16 [C,R] transpose-convert, batched over z --------
__global__ __launch_bounds__(256)
void tcvt_k(const float* __restrict__ in0, u16* __restrict__ out0, int R, int C) {
  __shared__ float t[32][33];
  const float* in = in0 + (size_t)blockIdx.z * R * C;
  u16* out = out0 + (size_t)blockIdx.z * R * C;
  int tx = threadIdx.x & 31, ty = threadIdx.x >> 5;
  long r0 = blockIdx.y * 32, c0 = blockIdx.x * 32;
#pragma unroll
  for (int i = 0; i < 4; ++i)
    t[ty + i*8][tx] = in[(r0 + ty + i*8) * (long)C + c0 + tx];
  __syncthreads();
#pragma unroll
  for (int i = 0; i < 4; ++i)
    out[(c0 + ty + i*8) * (long)R + r0 + tx] = f2b(t[tx][ty + i*8]);
}

// ---------------- 128x128 GEMM (in-proj / O-proj): simple 2-barrier --------
template<int EPI>
__global__ __launch_bounds__(256, 2)
void gemm_k(const u16* __restrict__ A, const u16* __restrict__ Bt,
            const float* __restrict__ bias,
            float* __restrict__ Cf, u16* __restrict__ Cb,
            const float* __restrict__ Res,
            int Ndim, int K, int scale_cols)
{
  __shared__ u16 As[128 * 32];
  __shared__ u16 Bs[128 * 32];
  const int tid = threadIdx.x;
  const int lane = tid & 63;
  const int wid = tid >> 6;
  const int wr = wid >> 1, wc = wid & 1;
  const int l15 = lane & 15, l4 = lane >> 4;
  const long arow0 = (long)blockIdx.x * 128;
  const long brow0 = (long)blockIdx.y * 128;

  f32x4 acc[4][4] = {};

  const int srow = tid >> 2;
  const int scol = (tid & 3) * 8;
  const u16* ga  = A  + (arow0 + srow) * K + scol;
  const u16* ga1 = ga + 64 * (long)K;
  const u16* gb  = Bt + (brow0 + srow) * K + scol;
  const u16* gb1 = gb + 64 * (long)K;
  u16* lA0 = &As[tid * 8];
  u16* lA1 = &As[2048 + tid * 8];
  u16* lB0 = &Bs[tid * 8];
  u16* lB1 = &Bs[2048 + tid * 8];

  for (int k0 = 0; k0 < K; k0 += 32) {
    gll16(ga + k0, lA0);
    gll16(ga1 + k0, lA1);
    gll16(gb + k0, lB0);
    gll16(gb1 + k0, lB1);
    __syncthreads();
    short8 af[4], bf[4];
#pragma unroll
    for (int m = 0; m < 4; ++m)
      af[m] = *(const short8*)&As[(wr*64 + m*16 + l15) * 32 + l4*8];
#pragma unroll
    for (int n = 0; n < 4; ++n)
      bf[n] = *(const short8*)&Bs[(wc*64 + n*16 + l15) * 32 + l4*8];
#pragma unroll
    for (int m = 0; m < 4; ++m)
#pragma unroll
      for (int n = 0; n < 4; ++n)
        acc[m][n] = __builtin_amdgcn_mfma_f32_16x16x32_bf16(af[m], bf[n], acc[m][n], 0, 0, 0);
    __syncthreads();
  }

  const int crow = wr*64 + l4*4;
  const int ccol = wc*64 + l15;
#pragma unroll
  for (int m = 0; m < 4; ++m) {
#pragma unroll
    for (int n = 0; n < 4; ++n) {
      const int col = (int)brow0 + ccol + n*16;
      const float bv = bias[col];
      const float sc = (EPI == 1 && col < scale_cols) ? SCALE_ : 1.0f;
#pragma unroll
      for (int r = 0; r < 4; ++r) {
        const long row = arow0 + crow + m*16 + r;
        float v = acc[m][n][r] + bv;
        if (EPI == 1) {
          Cb[row * Ndim + col] = f2b(v * sc);
        } else if (EPI == 0) {
          Cf[row * Ndim + col] = v;
          Cb[row * Ndim + col] = f2b(v);
        } else {
          Cf[row * Ndim + col] = v + Res[row * Ndim + col];
        }
      }
    }
  }
}

// ---------------- 256x256 8-phase GEMM for QKV (M=8192,N=3072,K=1024) -------
__global__ __launch_bounds__(512, 1)
void gemm8_k(const u16* __restrict__ A, const u16* __restrict__ Bt,
             const float* __restrict__ bias, u16* __restrict__ Cb)
{
  constexpr int K = 1024, N = 3 * H_;
  constexpr int NT = K / 64;                 // 16 K-tiles
  __shared__ u16 lds[8][8192];               // [buf*4 + op*2 + half][128*64]

  const int tid = threadIdx.x;
  const int lane = tid & 63;
  const int wid = tid >> 6;
  const int wm = wid >> 2, wn = wid & 3;
  const int l15 = lane & 15, l4 = lane >> 4;

  const int bid = blockIdx.x;                // 384 blocks; 384 % 8 == 0
  const int swz = (bid & 7) * 48 + (bid >> 3);
  const long arow0 = (long)(swz & 31) * 256;
  const long brow0 = (long)(swz >> 5) * 256;

  f32x4 acc[8][4] = {};
  short8 bfr[4][2];
  short8 afr[2][2];

  auto stage = [&](int buf, int op, int half, int kt) {
    const u16* src = op ? Bt : A;
    const long rb = (op ? brow0 : arow0) + half * 128;
    u16* dst = lds[buf*4 + op*2 + half];
#pragma unroll
    for (int ld = 0; ld < 2; ++ld) {
      int p = ld * 512 + tid;
      int row = p >> 3;
      int kc = (p & 7) ^ (row & 7);          // inverse swizzle on source
      gll16(src + (rb + row) * (long)K + kt * 64 + kc * 8, (char*)dst + p * 16);
    }
  };
  auto readB = [&](int buf) {
    const char* base = (const char*)lds[buf*4 + 2 + (wn >> 1)];
#pragma unroll
    for (int n = 0; n < 4; ++n)
#pragma unroll
      for (int ks = 0; ks < 2; ++ks) {
        int rh = (wn & 1) * 64 + n * 16 + l15;
        int byt = rh * 128 + ((((ks*4 + l4) * 16)) ^ ((rh & 7) << 4));
        bfr[n][ks] = *(const short8*)(base + byt);
      }
  };
  auto readA = [&](int buf, int q) {
    const char* base = (const char*)lds[buf*4 + wm];
#pragma unroll
    for (int j = 0; j < 2; ++j)
#pragma unroll
      for (int ks = 0; ks < 2; ++ks) {
        int rh = (2*q + j) * 16 + l15;
        int byt = rh * 128 + ((((ks*4 + l4) * 16)) ^ ((rh & 7) << 4));
        afr[j][ks] = *(const short8*)(base + byt);
      }
  };
  auto mm = [&](int q) {
    __builtin_amdgcn_s_setprio(1);
#pragma unroll
    for (int j = 0; j < 2; ++j)
#pragma unroll
      for (int n = 0; n < 4; ++n)
#pragma unroll
        for (int ks = 0; ks < 2; ++ks)
          acc[2*q+j][n] = __builtin_amdgcn_mfma_f32_16x16x32_bf16(
              afr[j][ks], bfr[n][ks], acc[2*q+j][n], 0, 0, 0);
    __builtin_amdgcn_s_setprio(0);
  };

#define PH(bufc, q, doB, sb, so, sh, st, doV)                     \
    readA(bufc, q); if (doB) readB(bufc);                         \
    stage(sb, so, sh, st);                                        \
    __builtin_amdgcn_s_barrier();                                 \
    asm volatile("s_waitcnt lgkmcnt(0)" ::: "memory");            \
    __builtin_amdgcn_sched_barrier(0);                            \
    mm(q);                                                        \
    if (doV) asm volatile("s_waitcnt vmcnt(4)" ::: "memory");     \
    __builtin_amdgcn_s_barrier();

  // prologue: tile0 all halves -> buf0; tile1 B halves -> buf1 (12 loads)
  stage(0,0,0,0); stage(0,0,1,0); stage(0,1,0,0); stage(0,1,1,0);
  stage(1,1,0,1); stage(1,1,1,1);
  asm volatile("s_waitcnt vmcnt(4)" ::: "memory");   // tile0 landed
  __builtin_amdgcn_s_barrier();

  const int niter = NT / 2;
  for (int i = 0; i < niter; ++i) {
    const int t1 = 2*i + 1;
    const int t2 = (2*i + 2 < NT) ? 2*i + 2 : NT - 1;   // clamped dummy stages
    const int t3 = (2*i + 3 < NT) ? 2*i + 3 : NT - 1;   // keep vmcnt counts
    PH(0, 0, true , 1, 0, 0, t1, false)   // compute tile 2i   q0, stage A0(2i+1)
    PH(0, 1, false, 1, 0, 1, t1, false)   //                   q1, stage A1(2i+1)
    PH(0, 2, false, 0, 1, 0, t2, false)   //                   q2, stage B0(2i+2)
    PH(0, 3, false, 0, 1, 1, t2, true )   //                   q3, stage B1(2i+2)
    PH(1, 0, true , 0, 0, 0, t2, false)   // compute tile 2i+1 q0, stage A0(2i+2)
    PH(1, 1, false, 0, 0, 1, t2, false)   //                   q1, stage A1(2i+2)
    PH(1, 2, false, 1, 1, 0, t3, false)   //                   q2, stage B0(2i+3)
    PH(1, 3, false, 1, 1, 1, t3, true )   //                   q3, stage B1(2i+3)
  }
#undef PH

  const long crow0 = arow0 + wm * 128;
  const int  ccol0 = (int)brow0 + wn * 64;
#pragma unroll
  for (int m = 0; m < 8; ++m) {
#pragma unroll
    for (int n = 0; n < 4; ++n) {
      const int col = ccol0 + n * 16 + l15;
      const float bv = bias[col];
      const float sc = (col < H_) ? SCALE_ : 1.0f;
#pragma unroll
      for (int r = 0; r < 4; ++r) {
        const long row = crow0 + m * 16 + l4 * 4 + r;
        Cb[row * N + col] = f2b((acc[m][n][r] + bv) * sc);
      }
    }
  }
}

// ------------- flash attention v3: 32x32 MFMA, in-register softmax ----------
__global__ __launch_bounds__(512)
void attn_k(const u16* __restrict__ qkv, u16* __restrict__ ob)
{
  __shared__ u16 Ks[2][4096];   // [64 kv][64 d], XOR-swizzled content
  __shared__ u16 Vs[2][4096];   // [64 d][64 kv] transposed, XOR-swizzled

  const int tid = threadIdx.x, lane = tid & 63, wid = tid >> 6;
  const int l31 = lane & 31, hi = lane >> 5;

  const int blk = blockIdx.x;
  const int xcd = blk & 7, slot = blk >> 3;
  const int bh = xcd + ((slot >> 2) << 3);   // head 0..127
  const int qx = slot & 3;                   // q-tile 0..3 (256 rows each)
  const int b = bh >> 4, nh = bh & 15;
  const int q0 = qx * 256 + wid * 32;

  const int RS = 3 * H_;
  const long base = (long)b * S_ * RS;
  const u16* Qg = qkv + base + nh * HD_;
  const u16* Kg = qkv + base + H_ + nh * HD_;
  const u16* Vg = qkv + base + 2 * H_ + nh * HD_;

  short8 qf[4];
#pragma unroll
  for (int ks = 0; ks < 4; ++ks)
    qf[ks] = *(const short8*)&Qg[(long)(q0 + l31) * RS + ks*16 + hi*8];

  float m_ = -1e30f, l_ = 0.f;
  f32x16 o0 = {}, o1 = {};

  const int krow = tid >> 3, kc = tid & 7;
  const int ksc = kc ^ (krow & 7);
  const long kgoff = (long)krow * RS + ksc * 8;
  const int vd = tid & 63, vch = tid >> 6;
  const int vbyt = (vd*128 + vch*16) ^ ((vd & 7) << 4);

  {
    gll16(Kg + kgoff, (char*)&Ks[0][0] + tid*16);
    union { u16 u[8]; short8 v; } tv;
#pragma unroll
    for (int j = 0; j < 8; ++j)
      tv.u[j] = Vg[(long)(vch*8 + j) * RS + vd];
    *(short8*)((char*)&Vs[0][0] + vbyt) = tv.v;
  }
  __syncthreads();

  for (int t = 0; t < 16; ++t) {
    const int cur = t & 1, nxt = cur ^ 1;
    union { u16 u[8]; short8 v; } ta;
    if (t < 15) {
      const long kv1 = (long)(t + 1) * 64;
      gll16(Kg + kv1 * RS + kgoff, (char*)&Ks[nxt][0] + tid*16);
#pragma unroll
      for (int j = 0; j < 8; ++j)
        ta.u[j] = Vg[(kv1 + vch*8 + j) * RS + vd];
    }

    f32x16 s0 = {}, s1 = {};
    __builtin_amdgcn_s_setprio(1);
#pragma unroll
    for (int ks = 0; ks < 4; ++ks) {
      const int koff = ks*32 + hi*16;
      const int by0 = (l31*128 + koff) ^ ((l31 & 7) << 4);
      short8 kf0 = *(const short8*)((const char*)&Ks[cur][0] + by0);
      s0 = __builtin_amdgcn_mfma_f32_32x32x16_bf16(kf0, qf[ks], s0, 0, 0, 0);
      const int by1 = ((32 + l31)*128 + koff) ^ ((l31 & 7) << 4);
      short8 kf1 = *(const short8*)((const char*)&Ks[cur][0] + by1);
      s1 = __builtin_amdgcn_mfma_f32_32x32x16_bf16(kf1, qf[ks], s1, 0, 0, 0);
    }
    __builtin_amdgcn_s_setprio(0);

    float tmax = -1e30f;
#pragma unroll
    for (int r = 0; r < 16; ++r) tmax = fmaxf(tmax, fmaxf(s0[r], s1[r]));
    tmax = fmaxf(tmax, __shfl_xor(tmax, 32));
    if (!__all(tmax <= m_ + 8.f)) {
      const float mnew = fmaxf(m_, tmax);
      const float corr = __expf(m_ - mnew);
      m_ = mnew; l_ *= corr;
#pragma unroll
      for (int r = 0; r < 16; ++r) {
        float cr = __shfl(corr, (r&3) + 8*(r>>2) + 4*hi);
        o0[r] *= cr; o1[r] *= cr;
      }
    }
    float sum = 0.f;
#pragma unroll
    for (int r = 0; r < 16; ++r) {
      float p0 = __expf(s0[r] - m_);
      float p1 = __expf(s1[r] - m_);
      s0[r] = p0; s1[r] = p1;
      sum += p0 + p1;
    }
    sum += __shfl_xor(sum, 32);
    l_ += sum;

    short8 pa[4];
#pragma unroll
    for (int ks2 = 0; ks2 < 2; ++ks2) {
      const int r0 = 8 * ks2;
      u32 A0 = cvtpk(s0[r0+0], s0[r0+1]), A1 = cvtpk(s0[r0+2], s0[r0+3]);
      u32 B0 = cvtpk(s0[r0+4], s0[r0+5]), B1 = cvtpk(s0[r0+6], s0[r0+7]);
      uint2v w02 = __builtin_amdgcn_permlane32_swap(A0, B0, false, false);
      uint2v w13 = __builtin_amdgcn_permlane32_swap(A1, B1, false, false);
      union { u32 w[4]; short8 v; } u_;
      u_.w[0] = w02.x; u_.w[1] = w13.x; u_.w[2] = w02.y; u_.w[3] = w13.y;
      pa[ks2] = u_.v;
    }
#pragma unroll
    for (int ks2 = 0; ks2 < 2; ++ks2) {
      const int r0 = 8 * ks2;
      u32 A0 = cvtpk(s1[r0+0], s1[r0+1]), A1 = cvtpk(s1[r0+2], s1[r0+3]);
      u32 B0 = cvtpk(s1[r0+4], s1[r0+5]), B1 = cvtpk(s1[r0+6], s1[r0+7]);
      uint2v w02 = __builtin_amdgcn_permlane32_swap(A0, B0, false, false);
      uint2v w13 = __builtin_amdgcn_permlane32_swap(A1, B1, false, false);
      union { u32 w[4]; short8 v; } u_;
      u_.w[0] = w02.x; u_.w[1] = w13.x; u_.w[2] = w02.y; u_.w[3] = w13.y;
      pa[2 + ks2] = u_.v;
    }

    __builtin_amdgcn_s_setprio(1);
#pragma unroll
    for (int ks = 0; ks < 4; ++ks) {
      const int vb = ks*32 + hi*16;
      const int by0 = (l31*128 + vb) ^ ((l31 & 7) << 4);
      short8 v0 = *(const short8*)((const char*)&Vs[cur][0] + by0);
      o0 = __builtin_amdgcn_mfma_f32_32x32x16_bf16(pa[ks], v0, o0, 0, 0, 0);
      const int by1 = ((32 + l31)*128 + vb) ^ ((l31 & 7) << 4);
      short8 v1 = *(const short8*)((const char*)&Vs[cur][0] + by1);
      o1 = __builtin_amdgcn_mfma_f32_32x32x16_bf16(pa[ks], v1, o1, 0, 0, 0);
    }
    __builtin_amdgcn_s_setprio(0);

    if (t < 15) {
      *(short8*)((char*)&Vs[nxt][0] + vbyt) = ta.v;
      __syncthreads();
    }
  }

  const float linv = 1.0f / l_;
#pragma unroll
  for (int r = 0; r < 16; ++r) {
    const int rowq = (r&3) + 8*(r>>2) + 4*hi;
    const float li = __shfl(linv, rowq);
    const long srow = (long)(b * S_ + q0 + rowq);
    ob[srow * H_ + nh*HD_ + l31]      = f2b(o0[r] * li);
    ob[srow * H_ + nh*HD_ + 32 + l31] = f2b(o1[r] * li);
  }
}

// ---------------- LayerNorm over rows of H=1024 (optional pre-bias) ---------
__global__ __launch_bounds__(256)
void ln_k(const float* __restrict__ in, const float* __restrict__ g,
          const float* __restrict__ be, float* __restrict__ outf,
          u16* __restrict__ outb, const float* __restrict__ bias)
{
  const int row = blockIdx.x;
  const int tid = threadIdx.x;
  const float* x = in + (long)row * H_;
  f32x4 v = *(const f32x4*)&x[tid * 4];
  if (bias) {
    f32x4 bv = *(const f32x4*)&bias[tid * 4];
    v[0] += bv[0]; v[1] += bv[1]; v[2] += bv[2]; v[3] += bv[3];
  }
  float s  = v[0] + v[1] + v[2] + v[3];
  float ss = v[0]*v[0] + v[1]*v[1] + v[2]*v[2] + v[3]*v[3];
#pragma unroll
  for (int o = 1; o < 64; o <<= 1) {
    s  += __shfl_xor(s, o);
    ss += __shfl_xor(ss, o);
  }
  __shared__ float rs[4], rq[4];
  const int wid = tid >> 6;
  if ((tid & 63) == 0) { rs[wid] = s; rq[wid] = ss; }
  __syncthreads();
  float ts = rs[0] + rs[1] + rs[2] + rs[3];
  float tq = rq[0] + rq[1] + rq[2] + rq[3];
  const float mu = ts * (1.0f / H_);
  const float var = tq * (1.0f / H_) - mu * mu;
  const float rstd = rsqrtf(var + EPS_);
  const long obase = (long)row * H_ + tid * 4;
#pragma unroll
  for (int j = 0; j < 4; ++j) {
    int c = tid * 4 + j;
    float y = (v[j] - mu) * rstd * g[c] + be[c];
    outf[obase + j] = y;
    if (outb) outb[obase + j] = f2b(y);
  }
}

// ---------------- mean-pool over S (partials + atomic) ----------------
__global__ void pool_k(const float* __restrict__ hf, float* __restrict__ pooled) {
  const int c = blockIdx.x * 256 + threadIdx.x;
  const int b = blockIdx.y;
  const int s0 = blockIdx.z * 128;
  float s = 0.f;
  for (int t = 0; t < 128; ++t) s += hf[((long)(b * S_ + s0 + t)) * H_ + c];
  atomicAdd(&pooled[b * H_ + c], s * (1.0f / S_));
}

// ---------------- final GEMM: split-k atomic (latency fix) ------------------
// grid (H/64, B, 8 kslices) x 64 threads: wave reads 128 coalesced W rows.
__global__ void fgemm_k(const float* __restrict__ pooled, const float* __restrict__ W,
                        float* __restrict__ out) {
  const int n = blockIdx.x * 64 + threadIdx.x;
  const int b = blockIdx.y;
  const int k0 = blockIdx.z * 128;
  const float* pr = pooled + b * H_ + k0;
  const float* wr = W + (long)k0 * H_ + n;
  float s = 0.f;
#pragma unroll 8
  for (int k = 0; k < 128; ++k)
    s += pr[k] * wr[(long)k * H_];
  atomicAdd(&out[b * H_ + n], s);
}

extern "C" void kernel_launch(void* const* d_in, const int* in_sizes, int n_in,
                              void* d_out, int out_size, void* d_ws, size_t ws_size,
                              hipStream_t stream) {
  const float* x     = (const float*)d_in[0];
  const float* W_in  = (const float*)d_in[1];
  const float* b_in  = (const float*)d_in[2];
  const float* W_qkv = (const float*)d_in[3];
  const float* b_qkv = (const float*)d_in[4];
  const float* W_o   = (const float*)d_in[5];
  const float* b_o   = (const float*)d_in[6];
  const float* g1    = (const float*)d_in[7];
  const float* be1   = (const float*)d_in[8];
  const float* W_out = (const float*)d_in[9];
  const float* b_out = (const float*)d_in[10];
  const float* g2    = (const float*)d_in[11];
  const float* be2   = (const float*)d_in[12];
  float* outp = (float*)d_out;

  char* ws = (char*)d_ws;
  float* hf    = (float*)(ws + 0);            // 33.55 MB
  u16*   hb    = (u16*)(ws + 33554432);       // 16.78 MB
  u16*   qkvb  = (u16*)(ws + 50331648);       // 50.33 MB
  float* resf  = (float*)(ws + 50331648);     // aliases qkvb (disjoint in time)
  u16*   ob    = (u16*)(ws + 100663296);      // 16.78 MB
  u16*   xb    = (u16*)(ws + 100663296);      // aliases ob (xb dead before attn)
  u16*   WinT  = (u16*)(ws + 117440512);      // 1.05 MB
  u16*   WqkvT = (u16*)(ws + 118489088);      // 25.17 MB
  u16*   WoT   = (u16*)(ws + 143654912);      // 8.39 MB
  float* pooled= (float*)(ws + 152043520);
  float* tmpf  = (float*)(ws + 152076288);

  cvt_k<<<dim3(M_ * DIN_ / 1024), 256, 0, stream>>>(x, xb);
  tcvt_k<<<dim3(H_/32, DIN_/32, 1), 256, 0, stream>>>(W_in, WinT, DIN_, H_);
  tcvt_k<<<dim3(3*H_/32, H_/32, L_), 256, 0, stream>>>(W_qkv, WqkvT, H_, 3*H_);
  tcvt_k<<<dim3(H_/32, H_/32, L_), 256, 0, stream>>>(W_o, WoT, H_, H_);

  gemm_k<0><<<dim3(M_/128, H_/128), 256, 0, stream>>>(xb, WinT, b_in, hf, hb, nullptr, H_, DIN_, 0);

  for (int l = 0; l < L_; ++l) {
    gemm8_k<<<dim3((M_/256) * (3*H_/256)), 512, 0, stream>>>(hb, WqkvT + (size_t)l*3*H_*H_,
                                                             b_qkv + l*3*H_, qkvb);
    attn_k<<<dim3(512), 512, 0, stream>>>(qkvb, ob);
    gemm_k<2><<<dim3(M_/128, H_/128), 256, 0, stream>>>(ob, WoT + (size_t)l*H_*H_,
                                                        b_o + l*H_, resf, nullptr, hf,
                                                        H_, H_, 0);
    ln_k<<<dim3(M_), 256, 0, stream>>>(resf, g1 + l*H_, be1 + l*H_, hf, hb, nullptr);
  }

  hipMemsetAsync(pooled, 0, B_ * H_ * sizeof(float), stream);
  hipMemsetAsync(tmpf, 0, B_ * H_ * sizeof(float), stream);
  pool_k<<<dim3(H_/256, B_, 8), 256, 0, stream>>>(hf, pooled);
  fgemm_k<<<dim3(H_/64, B_, 8), 64, 0, stream>>>(pooled, W_out, tmpf);
  ln_k<<<dim3(B_), 256, 0, stream>>>(tmpf, g2, be2, outp, nullptr, b_out);
}